// Round 1
// baseline (346.907 us; speedup 1.0000x reference)
//
#include <hip/hip_runtime.h>
#include <math.h>

// Problem constants
#define S_LEN 2048
#define BATCH 8
#define EMBD  256
#define NHEAD 4
#define HDIM  64
#define WIN   64

// ---------------------------------------------------------------------------
// K1: fused embedding-gather + QKV projection GEMM.
// C[M=16384, N=768] = emb[text[m]] @ in_proj_w^T + b ; scatter to Q,K,V [B,H,S,D]
// BM=128, BN=128, BK=32, 256 threads, 8x8 register microtile.
// ---------------------------------------------------------------------------
__global__ __launch_bounds__(256) void k_qkv(
    const int* __restrict__ text, const float* __restrict__ emb,
    const float* __restrict__ w, const float* __restrict__ bias,
    float* __restrict__ Q, float* __restrict__ K, float* __restrict__ V)
{
    __shared__ float Xst[32][132];   // [k][m], padded
    __shared__ float Wst[32][132];   // [k][n], padded
    const int tid = threadIdx.x;
    const int tr = tid >> 4, tc = tid & 15;
    const int m0 = blockIdx.x * 128, n0 = blockIdx.y * 128;

    float acc[8][8];
#pragma unroll
    for (int r = 0; r < 8; ++r)
#pragma unroll
        for (int c = 0; c < 8; ++c) acc[r][c] = 0.f;

    for (int k0 = 0; k0 < 256; k0 += 32) {
        // stage X (gather emb rows): 128 rows x 8 float4
#pragma unroll
        for (int it = 0; it < 4; ++it) {
            int elem = it * 256 + tid;
            int m = elem >> 3, k4 = elem & 7;
            int tok = text[m0 + m];
            float4 x4 = *(const float4*)&emb[tok * 256 + k0 + k4 * 4];
            Xst[k4 * 4 + 0][m] = x4.x; Xst[k4 * 4 + 1][m] = x4.y;
            Xst[k4 * 4 + 2][m] = x4.z; Xst[k4 * 4 + 3][m] = x4.w;
        }
        // stage W: 128 rows x 8 float4
#pragma unroll
        for (int it = 0; it < 4; ++it) {
            int elem = it * 256 + tid;
            int n = elem >> 3, k4 = elem & 7;
            float4 w4 = *(const float4*)&w[(n0 + n) * 256 + k0 + k4 * 4];
            Wst[k4 * 4 + 0][n] = w4.x; Wst[k4 * 4 + 1][n] = w4.y;
            Wst[k4 * 4 + 2][n] = w4.z; Wst[k4 * 4 + 3][n] = w4.w;
        }
        __syncthreads();
#pragma unroll 8
        for (int kk = 0; kk < 32; ++kk) {
            float4 xa = *(float4*)&Xst[kk][tr * 8];
            float4 xb = *(float4*)&Xst[kk][tr * 8 + 4];
            float4 wa = *(float4*)&Wst[kk][tc * 8];
            float4 wb = *(float4*)&Wst[kk][tc * 8 + 4];
            float xs[8] = {xa.x, xa.y, xa.z, xa.w, xb.x, xb.y, xb.z, xb.w};
            float wv[8] = {wa.x, wa.y, wa.z, wa.w, wb.x, wb.y, wb.z, wb.w};
#pragma unroll
            for (int r = 0; r < 8; ++r)
#pragma unroll
                for (int c = 0; c < 8; ++c)
                    acc[r][c] = fmaf(xs[r], wv[c], acc[r][c]);
        }
        __syncthreads();
    }

    // epilogue: bias, q-scale, scatter to [B,H,S,D]
    const int sec = n0 >> 8;                    // 0=Q, 1=K, 2=V
    float* dst = sec == 0 ? Q : (sec == 1 ? K : V);
    const float scale = sec == 0 ? 0.125f : 1.0f;
    const int ebase = (n0 & 255) + tc * 8;      // 0..255, multiple of 8
    const int h = ebase >> 6, d = ebase & 63;   // same head for all 8 cols
    float bv[8];
#pragma unroll
    for (int c = 0; c < 8; ++c) bv[c] = bias[n0 + tc * 8 + c];
#pragma unroll
    for (int r = 0; r < 8; ++r) {
        int m = m0 + tr * 8 + r;
        int b = m >> 11, s = m & 2047;
        float* o = &dst[(((b * 4 + h) * 2048) + s) * 64 + d];
        float4 v0 = make_float4((acc[r][0] + bv[0]) * scale, (acc[r][1] + bv[1]) * scale,
                                (acc[r][2] + bv[2]) * scale, (acc[r][3] + bv[3]) * scale);
        float4 v1 = make_float4((acc[r][4] + bv[4]) * scale, (acc[r][5] + bv[5]) * scale,
                                (acc[r][6] + bv[6]) * scale, (acc[r][7] + bv[7]) * scale);
        *(float4*)o = v0;
        *(float4*)(o + 4) = v1;
    }
}

// ---------------------------------------------------------------------------
// K2: banded attention. Block = (b, h, 64 q-rows), 192-key staged window.
// Dynamic LDS layout (floats):
//   [0 .. 16895]        region A: Kst[64][196] + Qst[64][68]  (phase 1)
//                       then   Vs[192][68]                    (phase 3)
//                       then   Par[3][64][68]                 (cross-wave reduce)
//   [16896 .. 30719]    Pt[192][72]  (scores -> probs)
// Total 30720 floats = 122880 B dynamic + 2 KB static stats.
// ---------------------------------------------------------------------------
__global__ __launch_bounds__(256, 1) void k_attn(
    const float* __restrict__ Q, const float* __restrict__ K,
    const float* __restrict__ V, float* __restrict__ AO)
{
    extern __shared__ float lds[];
    float* Kst = lds;                 // [64][196] (transposed [d][j])
    float* Qst = lds + 12544;         // [64][68]  (transposed [d][q])
    float* Vs  = lds;                 // [192][68] (natural [j][d])
    float* Par = lds;                 // [3][64][68]
    float* Pt  = lds + 16896;         // [192][72] ([j][q])
    __shared__ float smax[4][64];
    __shared__ float ssum[4][64];

    const int tid = threadIdx.x;
    const int s0 = blockIdx.x * 64;
    const int h = blockIdx.y, b = blockIdx.z;
    const float* Qp = Q + (size_t)((b * 4 + h) * 2048) * 64;
    const float* Kp = K + (size_t)((b * 4 + h) * 2048) * 64;
    const float* Vp = V + (size_t)((b * 4 + h) * 2048) * 64;

    // stage Q transposed [d][q]
#pragma unroll
    for (int it = 0; it < 4; ++it) {
        int elem = it * 256 + tid;
        int m = elem >> 4, d4 = elem & 15;
        float4 q4 = *(const float4*)&Qp[(s0 + m) * 64 + d4 * 4];
        Qst[(d4 * 4 + 0) * 68 + m] = q4.x; Qst[(d4 * 4 + 1) * 68 + m] = q4.y;
        Qst[(d4 * 4 + 2) * 68 + m] = q4.z; Qst[(d4 * 4 + 3) * 68 + m] = q4.w;
    }
    // stage K transposed [d][j], keys s0-64 .. s0+127 (clamped; masked later)
#pragma unroll
    for (int it = 0; it < 12; ++it) {
        int elem = it * 256 + tid;
        int j = elem >> 4, d4 = elem & 15;
        int ks = s0 - 64 + j;
        ks = ks < 0 ? 0 : (ks > 2047 ? 2047 : ks);
        float4 k4 = *(const float4*)&Kp[ks * 64 + d4 * 4];
        Kst[(d4 * 4 + 0) * 196 + j] = k4.x; Kst[(d4 * 4 + 1) * 196 + j] = k4.y;
        Kst[(d4 * 4 + 2) * 196 + j] = k4.z; Kst[(d4 * 4 + 3) * 196 + j] = k4.w;
    }
    __syncthreads();

    // phase 1: scores, 4q x 12j microtile per thread
    const int qg = tid >> 4, jg = tid & 15;
    float sc[4][12];
#pragma unroll
    for (int r = 0; r < 4; ++r)
#pragma unroll
        for (int c = 0; c < 12; ++c) sc[r][c] = 0.f;
#pragma unroll 4
    for (int d = 0; d < 64; ++d) {
        float4 qv = *(float4*)&Qst[d * 68 + qg * 4];
        const float* kr = &Kst[d * 196 + jg * 12];
        float4 ka = *(float4*)kr;
        float4 kb = *(float4*)(kr + 4);
        float4 kc = *(float4*)(kr + 8);
        float qa[4] = {qv.x, qv.y, qv.z, qv.w};
        float kk[12] = {ka.x, ka.y, ka.z, ka.w, kb.x, kb.y, kb.z, kb.w,
                        kc.x, kc.y, kc.z, kc.w};
#pragma unroll
        for (int r = 0; r < 4; ++r)
#pragma unroll
            for (int c = 0; c < 12; ++c)
                sc[r][c] = fmaf(qa[r], kk[c], sc[r][c]);
    }
    // band mask + store scores to Pt[j][q]
#pragma unroll
    for (int c = 0; c < 12; ++c) {
        int j = jg * 12 + c;
        int ks = s0 - 64 + j;
        bool inr = (unsigned)ks < 2048u;
        float vals[4];
#pragma unroll
        for (int r = 0; r < 4; ++r) {
            int dd = (qg * 4 + r) + 64 - j;         // q_global - ks
            bool band = (dd >= -64) && (dd <= 64);
            vals[r] = (inr && band) ? sc[r][c] : -1e30f;
        }
        *(float4*)&Pt[j * 72 + qg * 4] = make_float4(vals[0], vals[1], vals[2], vals[3]);
    }
    __syncthreads();

    // stage V (overwrites Kst/Qst region)
#pragma unroll
    for (int it = 0; it < 12; ++it) {
        int elem = it * 256 + tid;
        int j = elem >> 4, d4 = elem & 15;
        int ks = s0 - 64 + j;
        ks = ks < 0 ? 0 : (ks > 2047 ? 2047 : ks);
        *(float4*)&Vs[j * 68 + d4 * 4] = *(const float4*)&Vp[ks * 64 + d4 * 4];
    }
    // phase 2: softmax over each Pt column (row of the score matrix)
    {
        const int q = tid & 63, part = tid >> 6;
        float mx = -1e30f;
        for (int jj = 0; jj < 48; ++jj)
            mx = fmaxf(mx, Pt[(part * 48 + jj) * 72 + q]);
        smax[part][q] = mx;
        __syncthreads();
        float M = fmaxf(fmaxf(smax[0][q], smax[1][q]), fmaxf(smax[2][q], smax[3][q]));
        float sum = 0.f;
        for (int jj = 0; jj < 48; ++jj) {
            int idx = (part * 48 + jj) * 72 + q;
            float p = __expf(Pt[idx] - M);
            Pt[idx] = p;
            sum += p;
        }
        ssum[part][q] = sum;
    }
    __syncthreads();

    // phase 3: PV, 8q x 8d microtile; key range split over 4 waves
    const int jp = tid >> 6, qg2 = (tid >> 3) & 7, dg = tid & 7;
    float pv[8][8];
#pragma unroll
    for (int r = 0; r < 8; ++r)
#pragma unroll
        for (int c = 0; c < 8; ++c) pv[r][c] = 0.f;
#pragma unroll 4
    for (int jj = 0; jj < 48; ++jj) {
        int j = jp * 48 + jj;
        const float* pr = &Pt[j * 72 + qg2 * 8];
        float4 pa = *(float4*)pr;
        float4 pb = *(float4*)(pr + 4);
        const float* vr = &Vs[j * 68 + dg * 8];
        float4 va = *(float4*)vr;
        float4 vb = *(float4*)(vr + 4);
        float pp[8] = {pa.x, pa.y, pa.z, pa.w, pb.x, pb.y, pb.z, pb.w};
        float vv[8] = {va.x, va.y, va.z, va.w, vb.x, vb.y, vb.z, vb.w};
#pragma unroll
        for (int r = 0; r < 8; ++r)
#pragma unroll
            for (int c = 0; c < 8; ++c)
                pv[r][c] = fmaf(pp[r], vv[c], pv[r][c]);
    }
    __syncthreads();   // all Vs reads done; region A reusable
    if (jp > 0) {
        float* base = &Par[(jp - 1) * 4352];
#pragma unroll
        for (int r = 0; r < 8; ++r) {
            float* o = &base[(qg2 * 8 + r) * 68 + dg * 8];
            *(float4*)o       = make_float4(pv[r][0], pv[r][1], pv[r][2], pv[r][3]);
            *(float4*)(o + 4) = make_float4(pv[r][4], pv[r][5], pv[r][6], pv[r][7]);
        }
    }
    __syncthreads();
    if (jp == 0) {
#pragma unroll
        for (int r = 0; r < 8; ++r) {
            int q = qg2 * 8 + r;
            float inv = 1.f / (ssum[0][q] + ssum[1][q] + ssum[2][q] + ssum[3][q]);
            float ov[8];
#pragma unroll
            for (int c = 0; c < 8; ++c) {
                float t = pv[r][c]
                        + Par[0 * 4352 + q * 68 + dg * 8 + c]
                        + Par[1 * 4352 + q * 68 + dg * 8 + c]
                        + Par[2 * 4352 + q * 68 + dg * 8 + c];
                ov[c] = t * inv;
            }
            float* o = &AO[((size_t)b * 2048 + s0 + q) * 256 + h * 64 + dg * 8];
            *(float4*)o       = make_float4(ov[0], ov[1], ov[2], ov[3]);
            *(float4*)(o + 4) = make_float4(ov[4], ov[5], ov[6], ov[7]);
        }
    }
}

// ---------------------------------------------------------------------------
// K3: out_proj GEMM fused with sequence max-pool (monotonic-uint atomicMax).
// C[M=16384, N=256] = AO @ out_proj_w^T + b ; ctx[b][n] = max over s.
// ---------------------------------------------------------------------------
__global__ __launch_bounds__(256) void k_oproj_max(
    const float* __restrict__ AO, const float* __restrict__ w,
    const float* __restrict__ bias, unsigned* __restrict__ CTX)
{
    __shared__ float Xst[32][132];
    __shared__ float Wst[32][132];
    __shared__ unsigned red[16][132];
    const int tid = threadIdx.x;
    const int tr = tid >> 4, tc = tid & 15;
    const int m0 = blockIdx.x * 128, n0 = blockIdx.y * 128;

    float acc[8][8];
#pragma unroll
    for (int r = 0; r < 8; ++r)
#pragma unroll
        for (int c = 0; c < 8; ++c) acc[r][c] = 0.f;

    for (int k0 = 0; k0 < 256; k0 += 32) {
#pragma unroll
        for (int it = 0; it < 4; ++it) {
            int elem = it * 256 + tid;
            int m = elem >> 3, k4 = elem & 7;
            float4 x4 = *(const float4*)&AO[(size_t)(m0 + m) * 256 + k0 + k4 * 4];
            Xst[k4 * 4 + 0][m] = x4.x; Xst[k4 * 4 + 1][m] = x4.y;
            Xst[k4 * 4 + 2][m] = x4.z; Xst[k4 * 4 + 3][m] = x4.w;
        }
#pragma unroll
        for (int it = 0; it < 4; ++it) {
            int elem = it * 256 + tid;
            int n = elem >> 3, k4 = elem & 7;
            float4 w4 = *(const float4*)&w[(n0 + n) * 256 + k0 + k4 * 4];
            Wst[k4 * 4 + 0][n] = w4.x; Wst[k4 * 4 + 1][n] = w4.y;
            Wst[k4 * 4 + 2][n] = w4.z; Wst[k4 * 4 + 3][n] = w4.w;
        }
        __syncthreads();
#pragma unroll 8
        for (int kk = 0; kk < 32; ++kk) {
            float4 xa = *(float4*)&Xst[kk][tr * 8];
            float4 xb = *(float4*)&Xst[kk][tr * 8 + 4];
            float4 wa = *(float4*)&Wst[kk][tc * 8];
            float4 wb = *(float4*)&Wst[kk][tc * 8 + 4];
            float xs[8] = {xa.x, xa.y, xa.z, xa.w, xb.x, xb.y, xb.z, xb.w};
            float wv[8] = {wa.x, wa.y, wa.z, wa.w, wb.x, wb.y, wb.z, wb.w};
#pragma unroll
            for (int r = 0; r < 8; ++r)
#pragma unroll
                for (int c = 0; c < 8; ++c)
                    acc[r][c] = fmaf(xs[r], wv[c], acc[r][c]);
        }
        __syncthreads();
    }

    const int b = m0 >> 11;   // 128-row tile never straddles a batch boundary
    float bv[8];
#pragma unroll
    for (int c = 0; c < 8; ++c) bv[c] = bias[n0 + tc * 8 + c];
    unsigned um[8];
#pragma unroll
    for (int c = 0; c < 8; ++c) um[c] = 0u;
#pragma unroll
    for (int r = 0; r < 8; ++r)
#pragma unroll
        for (int c = 0; c < 8; ++c) {
            float v = acc[r][c] + bv[c];
            unsigned bits = __float_as_uint(v);
            unsigned u = (bits & 0x80000000u) ? ~bits : (bits | 0x80000000u);
            um[c] = um[c] > u ? um[c] : u;
        }
#pragma unroll
    for (int c = 0; c < 8; ++c) red[tr][tc * 8 + c] = um[c];
    __syncthreads();
    if (tid < 128) {
        unsigned u = red[0][tid];
#pragma unroll
        for (int t = 1; t < 16; ++t) u = u > red[t][tid] ? u : red[t][tid];
        atomicMax(&CTX[b * 256 + n0 + tid], u);
    }
}

// ---------------------------------------------------------------------------
// K4a: fc1 + leaky_relu. 16 blocks: block = (row, half of 512 outputs).
// ---------------------------------------------------------------------------
__global__ __launch_bounds__(256) void k_fc1(
    const unsigned* __restrict__ CTX, const float* __restrict__ w,
    const float* __restrict__ bias, float* __restrict__ H1)
{
    __shared__ float cs[256];
    const int tid = threadIdx.x;
    const int row = blockIdx.x >> 1, half = blockIdx.x & 1;
    unsigned u = CTX[row * 256 + tid];
    unsigned bits = (u & 0x80000000u) ? (u & 0x7fffffffu) : ~u;
    cs[tid] = __uint_as_float(bits);
    __syncthreads();
    const int o = half * 256 + tid;
    float a = bias[o];
#pragma unroll 8
    for (int c4 = 0; c4 < 64; ++c4) {
        float4 w4 = *(const float4*)&w[o * 256 + c4 * 4];
        a = fmaf(w4.x, cs[c4 * 4 + 0], a);
        a = fmaf(w4.y, cs[c4 * 4 + 1], a);
        a = fmaf(w4.z, cs[c4 * 4 + 2], a);
        a = fmaf(w4.w, cs[c4 * 4 + 3], a);
    }
    H1[row * 512 + o] = a > 0.f ? a : 0.01f * a;
}

// ---------------------------------------------------------------------------
// K4b: fc2 + leaky_relu + fc3, single block.
// ---------------------------------------------------------------------------
__global__ __launch_bounds__(256) void k_head(
    const float* __restrict__ H1, const float* __restrict__ w2,
    const float* __restrict__ b2, const float* __restrict__ w3,
    const float* __restrict__ b3, float* __restrict__ out)
{
    __shared__ float H1s[8][516];
    __shared__ float H2s[8][260];
    const int tid = threadIdx.x;
    for (int i = tid; i < 4096; i += 256) H1s[i >> 9][i & 511] = H1[i];
    __syncthreads();
    float a2[8];
#pragma unroll
    for (int r = 0; r < 8; ++r) a2[r] = b2[tid];
    for (int c4 = 0; c4 < 128; ++c4) {
        float4 w4 = *(const float4*)&w2[tid * 512 + c4 * 4];
#pragma unroll
        for (int r = 0; r < 8; ++r) {
            a2[r] = fmaf(w4.x, H1s[r][c4 * 4 + 0], a2[r]);
            a2[r] = fmaf(w4.y, H1s[r][c4 * 4 + 1], a2[r]);
            a2[r] = fmaf(w4.z, H1s[r][c4 * 4 + 2], a2[r]);
            a2[r] = fmaf(w4.w, H1s[r][c4 * 4 + 3], a2[r]);
        }
    }
#pragma unroll
    for (int r = 0; r < 8; ++r) {
        float v = a2[r];
        H2s[r][tid] = v > 0.f ? v : 0.01f * v;
    }
    __syncthreads();
    if (tid < 160) {
        int r = tid / 20, o = tid % 20;
        float a = b3[o];
#pragma unroll 8
        for (int c4 = 0; c4 < 64; ++c4) {
            float4 w4 = *(const float4*)&w3[o * 256 + c4 * 4];
            a = fmaf(w4.x, H2s[r][c4 * 4 + 0], a);
            a = fmaf(w4.y, H2s[r][c4 * 4 + 1], a);
            a = fmaf(w4.z, H2s[r][c4 * 4 + 2], a);
            a = fmaf(w4.w, H2s[r][c4 * 4 + 3], a);
        }
        out[tid] = a;
    }
}

// ---------------------------------------------------------------------------
extern "C" void kernel_launch(void* const* d_in, const int* in_sizes, int n_in,
                              void* d_out, int out_size, void* d_ws, size_t ws_size,
                              hipStream_t stream)
{
    (void)in_sizes; (void)n_in; (void)out_size; (void)ws_size;
    const int*   text = (const int*)d_in[0];
    const float* emb  = (const float*)d_in[1];
    const float* ipw  = (const float*)d_in[2];
    const float* ipb  = (const float*)d_in[3];
    const float* opw  = (const float*)d_in[4];
    const float* opb  = (const float*)d_in[5];
    const float* f1w  = (const float*)d_in[6];
    const float* f1b  = (const float*)d_in[7];
    const float* f2w  = (const float*)d_in[8];
    const float* f2b  = (const float*)d_in[9];
    const float* f3w  = (const float*)d_in[10];
    const float* f3b  = (const float*)d_in[11];
    float* out = (float*)d_out;

    float* ws = (float*)d_ws;
    const size_t T = (size_t)BATCH * NHEAD * S_LEN * HDIM;   // 4194304 floats
    float* Q  = ws;
    float* K  = ws + T;
    float* V  = ws + 2 * T;
    float* AO = ws + 3 * T;
    unsigned* CTX = (unsigned*)(ws + 4 * T);                 // [8][256]
    float* H1 = (float*)(CTX + 2048);                        // [8][512]

    hipFuncSetAttribute((const void*)k_attn,
                        hipFuncAttributeMaxDynamicSharedMemorySize, 122880);

    hipMemsetAsync(CTX, 0, 2048 * sizeof(unsigned), stream);
    k_qkv<<<dim3(128, 6), 256, 0, stream>>>(text, emb, ipw, ipb, Q, K, V);
    k_attn<<<dim3(32, 4, 8), 256, 122880, stream>>>(Q, K, V, AO);
    k_oproj_max<<<dim3(128, 2), 256, 0, stream>>>(AO, opw, opb, CTX);
    k_fc1<<<16, 256, 0, stream>>>(CTX, f1w, f1b, H1);
    k_head<<<1, 256, 0, stream>>>(H1, f2w, f2b, f3w, f3b, out);
}

// Round 3
// 284.834 us; speedup vs baseline: 1.2179x; 1.2179x over previous
//
#include <hip/hip_runtime.h>
#include <math.h>

typedef __attribute__((ext_vector_type(4))) float f32x4;
typedef __attribute__((ext_vector_type(8))) short short8;

__device__ __forceinline__ ushort bf16r(float f) {
    unsigned u = __float_as_uint(f);
    return (ushort)((u + 0x7FFFu + ((u >> 16) & 1u)) >> 16);
}
__device__ __forceinline__ float bf2f(ushort h) {
    return __uint_as_float(((unsigned)h) << 16);
}

// ---------------------------------------------------------------------------
// K_embed: gather emb rows for all 16384 tokens, split fp32 -> (hi, lo) bf16.
// Xh/Xl: [16384][256] bf16.
// ---------------------------------------------------------------------------
__global__ __launch_bounds__(256) void k_embed(
    const int* __restrict__ text, const float* __restrict__ emb,
    ushort* __restrict__ Xh, ushort* __restrict__ Xl)
{
    int id = blockIdx.x * 256 + threadIdx.x;   // [0, 1048576)
    int row = id >> 6, f4 = id & 63;
    int tok = text[row];
    float4 x = *(const float4*)&emb[(size_t)tok * 256 + f4 * 4];
    ushort h0 = bf16r(x.x), h1 = bf16r(x.y), h2 = bf16r(x.z), h3 = bf16r(x.w);
    uint2 hh = make_uint2((unsigned)h0 | ((unsigned)h1 << 16),
                          (unsigned)h2 | ((unsigned)h3 << 16));
    uint2 ll = make_uint2((unsigned)bf16r(x.x - bf2f(h0)) | ((unsigned)bf16r(x.y - bf2f(h1)) << 16),
                          (unsigned)bf16r(x.z - bf2f(h2)) | ((unsigned)bf16r(x.w - bf2f(h3)) << 16));
    size_t o = (size_t)row * 256 + f4 * 4;
    *(uint2*)&Xh[o] = hh;
    *(uint2*)&Xl[o] = ll;
}

// ---------------------------------------------------------------------------
// K1: QKV GEMM via split-bf16 MFMA (acc += Ah*Bh + Ah*Bl + Al*Bh).
// C[16384,768] = X @ W^T + b -> Q,K,V fp32 [B,H,S,64] (Q pre-scaled by 1/8).
// BM=128, BN=128, BK=64, 256 thr (2x2 waves), 16x16x32 bf16 MFMA.
// LDS (dynamic, 64 KiB): Ah/Al/Bh/Bl each [128][64] bf16, XOR-swizzled.
// ---------------------------------------------------------------------------
__global__ __launch_bounds__(256) void k_qkv(
    const ushort* __restrict__ Xh, const ushort* __restrict__ Xl,
    const float* __restrict__ w, const float* __restrict__ bias,
    float* __restrict__ Q, float* __restrict__ K, float* __restrict__ V)
{
    extern __shared__ ushort lds[];
    ushort* Ah = lds;
    ushort* Al = lds + 8192;
    ushort* Bh = lds + 16384;
    ushort* Bl = lds + 24576;
    const int tid = threadIdx.x;
    const int lane = tid & 63, wv = tid >> 6;
    const int g = lane >> 4, c = lane & 15;
    const int wm = wv >> 1, wn = wv & 1;
    const int m0 = blockIdx.x * 128, n0 = blockIdx.y * 128;

    f32x4 acc[4][4];
#pragma unroll
    for (int mi = 0; mi < 4; ++mi)
#pragma unroll
        for (int ni = 0; ni < 4; ++ni) acc[mi][ni] = (f32x4){0.f, 0.f, 0.f, 0.f};

    for (int ki = 0; ki < 4; ++ki) {
        const int k0 = ki * 64;
        // stage A: copy pre-split X (8-elt chunks)
#pragma unroll
        for (int it = 0; it < 4; ++it) {
            int ch = it * 256 + tid;            // 1024 chunks
            int row = ch >> 3, c8 = ch & 7;
            int col = (c8 * 8) ^ ((row & 7) << 3);
            size_t src = (size_t)(m0 + row) * 256 + k0 + c8 * 8;
            *(uint4*)&Ah[row * 64 + col] = *(const uint4*)&Xh[src];
            *(uint4*)&Al[row * 64 + col] = *(const uint4*)&Xl[src];
        }
        // stage B: split fp32 weights on the fly (4-elt chunks)
#pragma unroll
        for (int it = 0; it < 8; ++it) {
            int ch = it * 256 + tid;            // 2048 chunks
            int row = ch >> 4, f4 = ch & 15;
            float4 x = *(const float4*)&w[(size_t)(n0 + row) * 256 + k0 + f4 * 4];
            ushort h0 = bf16r(x.x), h1 = bf16r(x.y), h2 = bf16r(x.z), h3 = bf16r(x.w);
            uint2 hh = make_uint2((unsigned)h0 | ((unsigned)h1 << 16),
                                  (unsigned)h2 | ((unsigned)h3 << 16));
            uint2 llv = make_uint2((unsigned)bf16r(x.x - bf2f(h0)) | ((unsigned)bf16r(x.y - bf2f(h1)) << 16),
                                   (unsigned)bf16r(x.z - bf2f(h2)) | ((unsigned)bf16r(x.w - bf2f(h3)) << 16));
            int col = (f4 * 4) ^ ((row & 7) << 3);
            *(uint2*)&Bh[row * 64 + col] = hh;
            *(uint2*)&Bl[row * 64 + col] = llv;
        }
        __syncthreads();
        const int swzc = (c & 7) << 3;
#pragma unroll
        for (int ks = 0; ks < 2; ++ks) {
            const int ko = ks * 32 + g * 8;
            short8 amh[4], aml[4], bnh[4], bnl[4];
#pragma unroll
            for (int mi = 0; mi < 4; ++mi) {
                int row = wm * 64 + mi * 16 + c;
                int off = row * 64 + (ko ^ swzc);
                amh[mi] = *(const short8*)&Ah[off];
                aml[mi] = *(const short8*)&Al[off];
            }
#pragma unroll
            for (int ni = 0; ni < 4; ++ni) {
                int row = wn * 64 + ni * 16 + c;
                int off = row * 64 + (ko ^ swzc);
                bnh[ni] = *(const short8*)&Bh[off];
                bnl[ni] = *(const short8*)&Bl[off];
            }
#pragma unroll
            for (int mi = 0; mi < 4; ++mi)
#pragma unroll
                for (int ni = 0; ni < 4; ++ni) {
                    acc[mi][ni] = __builtin_amdgcn_mfma_f32_16x16x32_bf16(amh[mi], bnh[ni], acc[mi][ni], 0, 0, 0);
                    acc[mi][ni] = __builtin_amdgcn_mfma_f32_16x16x32_bf16(amh[mi], bnl[ni], acc[mi][ni], 0, 0, 0);
                    acc[mi][ni] = __builtin_amdgcn_mfma_f32_16x16x32_bf16(aml[mi], bnh[ni], acc[mi][ni], 0, 0, 0);
                }
        }
        __syncthreads();
    }

    // epilogue: bias, q-scale, scatter fp32 to [B,H,S,64]
    const int sec = n0 >> 8;
    float* dst = sec == 0 ? Q : (sec == 1 ? K : V);
    const float scale = sec == 0 ? 0.125f : 1.0f;
#pragma unroll
    for (int ni = 0; ni < 4; ++ni) {
        int n = n0 + wn * 64 + ni * 16 + c;
        float bv = bias[n];
        int hh = (n & 255) >> 6, d = n & 63;
#pragma unroll
        for (int mi = 0; mi < 4; ++mi)
#pragma unroll
            for (int r = 0; r < 4; ++r) {
                int m = m0 + wm * 64 + mi * 16 + g * 4 + r;
                int bb = m >> 11, s = m & 2047;
                dst[(size_t)(((bb * 4 + hh) * 2048) + s) * 64 + d] =
                    (acc[mi][ni][r] + bv) * scale;
            }
    }
}

// ---------------------------------------------------------------------------
// K2: banded attention — ROUND-1 fp32 kernel verbatim (proven absmax 0.0),
// epilogue changed to emit AO pre-split as (hi, lo) bf16 for k_oproj.
// ---------------------------------------------------------------------------
__global__ __launch_bounds__(256, 1) void k_attn(
    const float* __restrict__ Q, const float* __restrict__ K,
    const float* __restrict__ V, ushort* __restrict__ AOh,
    ushort* __restrict__ AOl)
{
    extern __shared__ float flds[];
    float* Kst = flds;                 // [64][196] (transposed [d][j])
    float* Qst = flds + 12544;         // [64][68]  (transposed [d][q])
    float* Vs  = flds;                 // [192][68] (natural [j][d])
    float* Par = flds;                 // [3][64][68]
    float* Pt  = flds + 16896;         // [192][72] ([j][q])
    __shared__ float smax[4][64];
    __shared__ float ssum[4][64];

    const int tid = threadIdx.x;
    const int s0 = blockIdx.x * 64;
    const int h = blockIdx.y, b = blockIdx.z;
    const float* Qp = Q + (size_t)((b * 4 + h) * 2048) * 64;
    const float* Kp = K + (size_t)((b * 4 + h) * 2048) * 64;
    const float* Vp = V + (size_t)((b * 4 + h) * 2048) * 64;

    // stage Q transposed [d][q]
#pragma unroll
    for (int it = 0; it < 4; ++it) {
        int elem = it * 256 + tid;
        int m = elem >> 4, d4 = elem & 15;
        float4 q4 = *(const float4*)&Qp[(s0 + m) * 64 + d4 * 4];
        Qst[(d4 * 4 + 0) * 68 + m] = q4.x; Qst[(d4 * 4 + 1) * 68 + m] = q4.y;
        Qst[(d4 * 4 + 2) * 68 + m] = q4.z; Qst[(d4 * 4 + 3) * 68 + m] = q4.w;
    }
    // stage K transposed [d][j], keys s0-64 .. s0+127 (clamped; masked later)
#pragma unroll
    for (int it = 0; it < 12; ++it) {
        int elem = it * 256 + tid;
        int j = elem >> 4, d4 = elem & 15;
        int ks = s0 - 64 + j;
        ks = ks < 0 ? 0 : (ks > 2047 ? 2047 : ks);
        float4 k4 = *(const float4*)&Kp[ks * 64 + d4 * 4];
        Kst[(d4 * 4 + 0) * 196 + j] = k4.x; Kst[(d4 * 4 + 1) * 196 + j] = k4.y;
        Kst[(d4 * 4 + 2) * 196 + j] = k4.z; Kst[(d4 * 4 + 3) * 196 + j] = k4.w;
    }
    __syncthreads();

    // phase 1: scores, 4q x 12j microtile per thread
    const int qg = tid >> 4, jg = tid & 15;
    float sc[4][12];
#pragma unroll
    for (int r = 0; r < 4; ++r)
#pragma unroll
        for (int c = 0; c < 12; ++c) sc[r][c] = 0.f;
#pragma unroll 4
    for (int d = 0; d < 64; ++d) {
        float4 qv = *(float4*)&Qst[d * 68 + qg * 4];
        const float* kr = &Kst[d * 196 + jg * 12];
        float4 ka = *(float4*)kr;
        float4 kb = *(float4*)(kr + 4);
        float4 kc = *(float4*)(kr + 8);
        float qa[4] = {qv.x, qv.y, qv.z, qv.w};
        float kk[12] = {ka.x, ka.y, ka.z, ka.w, kb.x, kb.y, kb.z, kb.w,
                        kc.x, kc.y, kc.z, kc.w};
#pragma unroll
        for (int r = 0; r < 4; ++r)
#pragma unroll
            for (int c = 0; c < 12; ++c)
                sc[r][c] = fmaf(qa[r], kk[c], sc[r][c]);
    }
    // band mask + store scores to Pt[j][q]
#pragma unroll
    for (int c = 0; c < 12; ++c) {
        int j = jg * 12 + c;
        int ks = s0 - 64 + j;
        bool inr = (unsigned)ks < 2048u;
        float vals[4];
#pragma unroll
        for (int r = 0; r < 4; ++r) {
            int dd = (qg * 4 + r) + 64 - j;
            bool band = (dd >= -64) && (dd <= 64);
            vals[r] = (inr && band) ? sc[r][c] : -1e30f;
        }
        *(float4*)&Pt[j * 72 + qg * 4] = make_float4(vals[0], vals[1], vals[2], vals[3]);
    }
    __syncthreads();

    // stage V (overwrites Kst/Qst region)
#pragma unroll
    for (int it = 0; it < 12; ++it) {
        int elem = it * 256 + tid;
        int j = elem >> 4, d4 = elem & 15;
        int ks = s0 - 64 + j;
        ks = ks < 0 ? 0 : (ks > 2047 ? 2047 : ks);
        *(float4*)&Vs[j * 68 + d4 * 4] = *(const float4*)&Vp[ks * 64 + d4 * 4];
    }
    // phase 2: softmax over each Pt column (row of the score matrix)
    {
        const int q = tid & 63, part = tid >> 6;
        float mx = -1e30f;
        for (int jj = 0; jj < 48; ++jj)
            mx = fmaxf(mx, Pt[(part * 48 + jj) * 72 + q]);
        smax[part][q] = mx;
        __syncthreads();
        float M = fmaxf(fmaxf(smax[0][q], smax[1][q]), fmaxf(smax[2][q], smax[3][q]));
        float sum = 0.f;
        for (int jj = 0; jj < 48; ++jj) {
            int idx = (part * 48 + jj) * 72 + q;
            float p = __expf(Pt[idx] - M);
            Pt[idx] = p;
            sum += p;
        }
        ssum[part][q] = sum;
    }
    __syncthreads();

    // phase 3: PV, 8q x 8d microtile; key range split over 4 waves
    const int jp = tid >> 6, qg2 = (tid >> 3) & 7, dg = tid & 7;
    float pv[8][8];
#pragma unroll
    for (int r = 0; r < 8; ++r)
#pragma unroll
        for (int c = 0; c < 8; ++c) pv[r][c] = 0.f;
#pragma unroll 4
    for (int jj = 0; jj < 48; ++jj) {
        int j = jp * 48 + jj;
        const float* pr = &Pt[j * 72 + qg2 * 8];
        float4 pa = *(float4*)pr;
        float4 pb = *(float4*)(pr + 4);
        const float* vr = &Vs[j * 68 + dg * 8];
        float4 va = *(float4*)vr;
        float4 vb = *(float4*)(vr + 4);
        float pp[8] = {pa.x, pa.y, pa.z, pa.w, pb.x, pb.y, pb.z, pb.w};
        float vvv[8] = {va.x, va.y, va.z, va.w, vb.x, vb.y, vb.z, vb.w};
#pragma unroll
        for (int r = 0; r < 8; ++r)
#pragma unroll
            for (int c = 0; c < 8; ++c)
                pv[r][c] = fmaf(pp[r], vvv[c], pv[r][c]);
    }
    __syncthreads();
    if (jp > 0) {
        float* base = &Par[(jp - 1) * 4352];
#pragma unroll
        for (int r = 0; r < 8; ++r) {
            float* o = &base[(qg2 * 8 + r) * 68 + dg * 8];
            *(float4*)o       = make_float4(pv[r][0], pv[r][1], pv[r][2], pv[r][3]);
            *(float4*)(o + 4) = make_float4(pv[r][4], pv[r][5], pv[r][6], pv[r][7]);
        }
    }
    __syncthreads();
    if (jp == 0) {
#pragma unroll
        for (int r = 0; r < 8; ++r) {
            int q = qg2 * 8 + r;
            float inv = 1.f / (ssum[0][q] + ssum[1][q] + ssum[2][q] + ssum[3][q]);
            union { uint2 u[2]; ushort s[8]; } ho, lo;
#pragma unroll
            for (int c = 0; c < 8; ++c) {
                float t = pv[r][c]
                        + Par[0 * 4352 + q * 68 + dg * 8 + c]
                        + Par[1 * 4352 + q * 68 + dg * 8 + c]
                        + Par[2 * 4352 + q * 68 + dg * 8 + c];
                float v = t * inv;
                ushort hb = bf16r(v);
                ho.s[c] = hb;
                lo.s[c] = bf16r(v - bf2f(hb));
            }
            size_t oidx = ((size_t)b * 2048 + s0 + q) * 256 + h * 64 + dg * 8;
            *(uint4*)&AOh[oidx] = *(uint4*)&ho;
            *(uint4*)&AOl[oidx] = *(uint4*)&lo;
        }
    }
}

// ---------------------------------------------------------------------------
// K3: out_proj via split-bf16 MFMA, fused with sequence max-pool (atomicMax).
// A = AO (pre-split by attn epilogue), B = out_proj_w split on the fly.
// ---------------------------------------------------------------------------
__global__ __launch_bounds__(256) void k_oproj(
    const ushort* __restrict__ AOh, const ushort* __restrict__ AOl,
    const float* __restrict__ w, const float* __restrict__ bias,
    unsigned* __restrict__ CTX)
{
    extern __shared__ ushort lds[];
    ushort* Ah = lds;
    ushort* Al = lds + 8192;
    ushort* Bh = lds + 16384;
    ushort* Bl = lds + 24576;
    const int tid = threadIdx.x;
    const int lane = tid & 63, wv = tid >> 6;
    const int g = lane >> 4, c = lane & 15;
    const int wm = wv >> 1, wn = wv & 1;
    const int m0 = blockIdx.x * 128, n0 = blockIdx.y * 128;

    f32x4 acc[4][4];
#pragma unroll
    for (int mi = 0; mi < 4; ++mi)
#pragma unroll
        for (int ni = 0; ni < 4; ++ni) acc[mi][ni] = (f32x4){0.f, 0.f, 0.f, 0.f};

    for (int ki = 0; ki < 4; ++ki) {
        const int k0 = ki * 64;
#pragma unroll
        for (int it = 0; it < 4; ++it) {
            int ch = it * 256 + tid;
            int row = ch >> 3, c8 = ch & 7;
            int col = (c8 * 8) ^ ((row & 7) << 3);
            size_t src = (size_t)(m0 + row) * 256 + k0 + c8 * 8;
            *(uint4*)&Ah[row * 64 + col] = *(const uint4*)&AOh[src];
            *(uint4*)&Al[row * 64 + col] = *(const uint4*)&AOl[src];
        }
#pragma unroll
        for (int it = 0; it < 8; ++it) {
            int ch = it * 256 + tid;
            int row = ch >> 4, f4 = ch & 15;
            float4 x = *(const float4*)&w[(size_t)(n0 + row) * 256 + k0 + f4 * 4];
            ushort h0 = bf16r(x.x), h1 = bf16r(x.y), h2 = bf16r(x.z), h3 = bf16r(x.w);
            uint2 hh = make_uint2((unsigned)h0 | ((unsigned)h1 << 16),
                                  (unsigned)h2 | ((unsigned)h3 << 16));
            uint2 llv = make_uint2((unsigned)bf16r(x.x - bf2f(h0)) | ((unsigned)bf16r(x.y - bf2f(h1)) << 16),
                                   (unsigned)bf16r(x.z - bf2f(h2)) | ((unsigned)bf16r(x.w - bf2f(h3)) << 16));
            int col = (f4 * 4) ^ ((row & 7) << 3);
            *(uint2*)&Bh[row * 64 + col] = hh;
            *(uint2*)&Bl[row * 64 + col] = llv;
        }
        __syncthreads();
        const int swzc = (c & 7) << 3;
#pragma unroll
        for (int ks = 0; ks < 2; ++ks) {
            const int ko = ks * 32 + g * 8;
            short8 amh[4], aml[4], bnh[4], bnl[4];
#pragma unroll
            for (int mi = 0; mi < 4; ++mi) {
                int row = wm * 64 + mi * 16 + c;
                int off = row * 64 + (ko ^ swzc);
                amh[mi] = *(const short8*)&Ah[off];
                aml[mi] = *(const short8*)&Al[off];
            }
#pragma unroll
            for (int ni = 0; ni < 4; ++ni) {
                int row = wn * 64 + ni * 16 + c;
                int off = row * 64 + (ko ^ swzc);
                bnh[ni] = *(const short8*)&Bh[off];
                bnl[ni] = *(const short8*)&Bl[off];
            }
#pragma unroll
            for (int mi = 0; mi < 4; ++mi)
#pragma unroll
                for (int ni = 0; ni < 4; ++ni) {
                    acc[mi][ni] = __builtin_amdgcn_mfma_f32_16x16x32_bf16(amh[mi], bnh[ni], acc[mi][ni], 0, 0, 0);
                    acc[mi][ni] = __builtin_amdgcn_mfma_f32_16x16x32_bf16(amh[mi], bnl[ni], acc[mi][ni], 0, 0, 0);
                    acc[mi][ni] = __builtin_amdgcn_mfma_f32_16x16x32_bf16(aml[mi], bnh[ni], acc[mi][ni], 0, 0, 0);
                }
        }
        __syncthreads();
    }

    // epilogue: per-column max over this block's 128 rows -> atomicMax
    const int bidx = m0 >> 11;
#pragma unroll
    for (int ni = 0; ni < 4; ++ni) {
        int n = n0 + wn * 64 + ni * 16 + c;
        float mx = -1e30f;
#pragma unroll
        for (int mi = 0; mi < 4; ++mi)
#pragma unroll
            for (int r = 0; r < 4; ++r) mx = fmaxf(mx, acc[mi][ni][r]);
        mx += bias[n];
        mx = fmaxf(mx, __shfl_xor(mx, 16));
        mx = fmaxf(mx, __shfl_xor(mx, 32));
        if (lane < 16) {
            unsigned bits = __float_as_uint(mx);
            unsigned en = (bits & 0x80000000u) ? ~bits : (bits | 0x80000000u);
            atomicMax(&CTX[bidx * 256 + n], en);
        }
    }
}

// ---------------------------------------------------------------------------
// K4a: fc1 + leaky_relu (fp32) — round-1 verbatim.
// ---------------------------------------------------------------------------
__global__ __launch_bounds__(256) void k_fc1(
    const unsigned* __restrict__ CTX, const float* __restrict__ w,
    const float* __restrict__ bias, float* __restrict__ H1)
{
    __shared__ float cs[256];
    const int tid = threadIdx.x;
    const int row = blockIdx.x >> 1, half = blockIdx.x & 1;
    unsigned u = CTX[row * 256 + tid];
    unsigned bits = (u & 0x80000000u) ? (u & 0x7fffffffu) : ~u;
    cs[tid] = __uint_as_float(bits);
    __syncthreads();
    const int o = half * 256 + tid;
    float a = bias[o];
#pragma unroll 8
    for (int c4 = 0; c4 < 64; ++c4) {
        float4 w4 = *(const float4*)&w[o * 256 + c4 * 4];
        a = fmaf(w4.x, cs[c4 * 4 + 0], a);
        a = fmaf(w4.y, cs[c4 * 4 + 1], a);
        a = fmaf(w4.z, cs[c4 * 4 + 2], a);
        a = fmaf(w4.w, cs[c4 * 4 + 3], a);
    }
    H1[row * 512 + o] = a > 0.f ? a : 0.01f * a;
}

// ---------------------------------------------------------------------------
// K4b: fc2 + leaky_relu + fc3, single block (fp32) — round-1 verbatim.
// ---------------------------------------------------------------------------
__global__ __launch_bounds__(256) void k_head(
    const float* __restrict__ H1, const float* __restrict__ w2,
    const float* __restrict__ b2, const float* __restrict__ w3,
    const float* __restrict__ b3, float* __restrict__ out)
{
    __shared__ float H1s[8][516];
    __shared__ float H2s[8][260];
    const int tid = threadIdx.x;
    for (int i = tid; i < 4096; i += 256) H1s[i >> 9][i & 511] = H1[i];
    __syncthreads();
    float a2[8];
#pragma unroll
    for (int r = 0; r < 8; ++r) a2[r] = b2[tid];
    for (int c4 = 0; c4 < 128; ++c4) {
        float4 w4 = *(const float4*)&w2[tid * 512 + c4 * 4];
#pragma unroll
        for (int r = 0; r < 8; ++r) {
            a2[r] = fmaf(w4.x, H1s[r][c4 * 4 + 0], a2[r]);
            a2[r] = fmaf(w4.y, H1s[r][c4 * 4 + 1], a2[r]);
            a2[r] = fmaf(w4.z, H1s[r][c4 * 4 + 2], a2[r]);
            a2[r] = fmaf(w4.w, H1s[r][c4 * 4 + 3], a2[r]);
        }
    }
#pragma unroll
    for (int r = 0; r < 8; ++r) {
        float v = a2[r];
        H2s[r][tid] = v > 0.f ? v : 0.01f * v;
    }
    __syncthreads();
    if (tid < 160) {
        int r = tid / 20, o = tid % 20;
        float a = b3[o];
#pragma unroll 8
        for (int c4 = 0; c4 < 64; ++c4) {
            float4 w4 = *(const float4*)&w3[o * 256 + c4 * 4];
            a = fmaf(w4.x, H2s[r][c4 * 4 + 0], a);
            a = fmaf(w4.y, H2s[r][c4 * 4 + 1], a);
            a = fmaf(w4.z, H2s[r][c4 * 4 + 2], a);
            a = fmaf(w4.w, H2s[r][c4 * 4 + 3], a);
        }
        out[tid] = a;
    }
}

// ---------------------------------------------------------------------------
extern "C" void kernel_launch(void* const* d_in, const int* in_sizes, int n_in,
                              void* d_out, int out_size, void* d_ws, size_t ws_size,
                              hipStream_t stream)
{
    (void)in_sizes; (void)n_in; (void)out_size; (void)ws_size;
    const int*   text = (const int*)d_in[0];
    const float* emb  = (const float*)d_in[1];
    const float* ipw  = (const float*)d_in[2];
    const float* ipb  = (const float*)d_in[3];
    const float* opw  = (const float*)d_in[4];
    const float* opb  = (const float*)d_in[5];
    const float* f1w  = (const float*)d_in[6];
    const float* f1b  = (const float*)d_in[7];
    const float* f2w  = (const float*)d_in[8];
    const float* f2b  = (const float*)d_in[9];
    const float* f3w  = (const float*)d_in[10];
    const float* f3b  = (const float*)d_in[11];
    float* out = (float*)d_out;

    // workspace layout (total 67,133,440 B == round-1's proven footprint)
    unsigned char* w8 = (unsigned char*)d_ws;
    float* Qf = (float*)(w8);                       // 16 MiB
    float* Kf = (float*)(w8 + 16777216);            // 16 MiB
    float* Vf = (float*)(w8 + 33554432);            // 16 MiB
    ushort* XAh = (ushort*)(w8 + 50331648);         // 8 MiB: Xh, then AOh
    ushort* XAl = (ushort*)(w8 + 58720256);         // 8 MiB: Xl, then AOl
    unsigned* CTX = (unsigned*)(w8 + 67108864);     // 8 KiB
    float* H1 = (float*)(w8 + 67117056);            // 16 KiB

    hipFuncSetAttribute((const void*)k_qkv,
                        hipFuncAttributeMaxDynamicSharedMemorySize, 65536);
    hipFuncSetAttribute((const void*)k_oproj,
                        hipFuncAttributeMaxDynamicSharedMemorySize, 65536);
    hipFuncSetAttribute((const void*)k_attn,
                        hipFuncAttributeMaxDynamicSharedMemorySize, 122880);

    hipMemsetAsync(CTX, 0, 8192, stream);
    k_embed<<<4096, 256, 0, stream>>>(text, emb, XAh, XAl);
    k_qkv<<<dim3(128, 6), 256, 65536, stream>>>(XAh, XAl, ipw, ipb, Qf, Kf, Vf);
    k_attn<<<dim3(32, 4, 8), 256, 122880, stream>>>(Qf, Kf, Vf, XAh, XAl);
    k_oproj<<<dim3(128, 2), 256, 65536, stream>>>(XAh, XAl, opw, opb, CTX);
    k_fc1<<<16, 256, 0, stream>>>(CTX, f1w, f1b, H1);
    k_head<<<1, 256, 0, stream>>>(H1, f2w, f2b, f3w, f3b, out);
}

// Round 5
// 232.695 us; speedup vs baseline: 1.4908x; 1.2241x over previous
//
#include <hip/hip_runtime.h>
#include <math.h>

typedef __attribute__((ext_vector_type(4))) float f32x4;
typedef __attribute__((ext_vector_type(8))) short short8;

__device__ __forceinline__ ushort bf16r(float f) {
    unsigned u = __float_as_uint(f);
    return (ushort)((u + 0x7FFFu + ((u >> 16) & 1u)) >> 16);
}
__device__ __forceinline__ unsigned pack2(float lo, float hi) {
    return (unsigned)bf16r(lo) | ((unsigned)bf16r(hi) << 16);
}

// ---------------------------------------------------------------------------
// K1: fused embedding-gather + QKV GEMM, plain bf16 MFMA.
// C[16384,768] = emb[text[m]] @ W^T + b.
// Outputs: Qb (pre-scaled 1/8), Kb bf16 [B,H,S,64]; V written ONLY transposed
// as VTb bf16 [B,H,64,S].
// BM=128, BN=128, BK=64, 256 thr (2x2 waves), 16x16x32 MFMA (proven maps).
// ---------------------------------------------------------------------------
__global__ __launch_bounds__(256) void k_qkv(
    const int* __restrict__ text, const float* __restrict__ emb,
    const float* __restrict__ w, const float* __restrict__ bias,
    ushort* __restrict__ Qb, ushort* __restrict__ Kb, ushort* __restrict__ VTb)
{
    __shared__ ushort Asm[8192];   // [128][64] bf16, XOR-swizzled
    __shared__ ushort Bsm[8192];
    const int tid = threadIdx.x;
    const int lane = tid & 63, wv = tid >> 6;
    const int g = lane >> 4, c = lane & 15;
    const int wm = wv >> 1, wn = wv & 1;
    const int m0 = blockIdx.x * 128, n0 = blockIdx.y * 128;

    f32x4 acc[4][4];
#pragma unroll
    for (int mi = 0; mi < 4; ++mi)
#pragma unroll
        for (int ni = 0; ni < 4; ++ni) acc[mi][ni] = (f32x4){0.f, 0.f, 0.f, 0.f};

    for (int ki = 0; ki < 4; ++ki) {
        const int k0 = ki * 64;
        // stage A: gather emb rows fp32 -> bf16 (proven gather-in-staging)
#pragma unroll
        for (int it = 0; it < 8; ++it) {
            int ch = it * 256 + tid;            // 2048 chunks of 4 floats
            int row = ch >> 4, f4 = ch & 15;
            int tok = text[m0 + row];
            float4 x = *(const float4*)&emb[(size_t)tok * 256 + k0 + f4 * 4];
            uint2 pk = make_uint2(pack2(x.x, x.y), pack2(x.z, x.w));
            *(uint2*)&Asm[row * 64 + ((f4 * 4) ^ ((row & 7) << 3))] = pk;
        }
        // stage B: fp32 weights -> bf16
#pragma unroll
        for (int it = 0; it < 8; ++it) {
            int ch = it * 256 + tid;
            int row = ch >> 4, f4 = ch & 15;
            float4 x = *(const float4*)&w[(size_t)(n0 + row) * 256 + k0 + f4 * 4];
            uint2 pk = make_uint2(pack2(x.x, x.y), pack2(x.z, x.w));
            *(uint2*)&Bsm[row * 64 + ((f4 * 4) ^ ((row & 7) << 3))] = pk;
        }
        __syncthreads();
#pragma unroll
        for (int ks = 0; ks < 2; ++ks) {
            const int ko = ks * 32 + g * 8;
            short8 am[4], bn[4];
#pragma unroll
            for (int mi = 0; mi < 4; ++mi) {
                int row = wm * 64 + mi * 16 + c;
                am[mi] = *(const short8*)&Asm[row * 64 + (ko ^ ((row & 7) << 3))];
            }
#pragma unroll
            for (int ni = 0; ni < 4; ++ni) {
                int row = wn * 64 + ni * 16 + c;
                bn[ni] = *(const short8*)&Bsm[row * 64 + (ko ^ ((row & 7) << 3))];
            }
#pragma unroll
            for (int mi = 0; mi < 4; ++mi)
#pragma unroll
                for (int ni = 0; ni < 4; ++ni)
                    acc[mi][ni] = __builtin_amdgcn_mfma_f32_16x16x32_bf16(
                        am[mi], bn[ni], acc[mi][ni], 0, 0, 0);
        }
        __syncthreads();
    }

    // epilogue
    const int sec = n0 >> 8;                    // 0=Q, 1=K, 2=V
    if (sec < 2) {
        ushort* dst = sec == 0 ? Qb : Kb;
        const float scale = sec == 0 ? 0.125f : 1.0f;
#pragma unroll
        for (int ni = 0; ni < 4; ++ni) {
            int n = n0 + wn * 64 + ni * 16 + c;
            float bv = bias[n];
            int h = (n >> 6) & 3, d = n & 63;
#pragma unroll
            for (int mi = 0; mi < 4; ++mi)
#pragma unroll
                for (int r = 0; r < 4; ++r) {
                    int m = m0 + wm * 64 + mi * 16 + g * 4 + r;
                    int bb = m >> 11, s = m & 2047;
                    dst[(size_t)((bb * 4 + h) * 2048 + s) * 64 + d] =
                        bf16r((acc[mi][ni][r] + bv) * scale);
                }
        }
    } else {
        // V: write transposed [B,H,64,S]; 4 consecutive s pack into uint2
#pragma unroll
        for (int ni = 0; ni < 4; ++ni) {
            int n = n0 + wn * 64 + ni * 16 + c;
            float bv = bias[n];
            int h = (n >> 6) & 3, d = n & 63;
#pragma unroll
            for (int mi = 0; mi < 4; ++mi) {
                int sb = m0 + wm * 64 + mi * 16 + g * 4;
                int bb = sb >> 11, s = sb & 2047;
                float v0 = acc[mi][ni][0] + bv, v1 = acc[mi][ni][1] + bv;
                float v2 = acc[mi][ni][2] + bv, v3 = acc[mi][ni][3] + bv;
                uint2 pk = make_uint2(pack2(v0, v1), pack2(v2, v3));
                *(uint2*)&VTb[(size_t)((bb * 4 + h) * 64 + d) * 2048 + s] = pk;
            }
        }
    }
}

// ---------------------------------------------------------------------------
// K2: banded attention, plain bf16 MFMA, proven fragment maps only.
// Block = (64 q-rows, h, b); 192-key window; 4 waves = 4 q-slices of 16.
// LDS 58,368 B -> 2 blocks/CU. Psm overlays Qsm+Ksm after barrier #1.
// ---------------------------------------------------------------------------
__global__ __launch_bounds__(256) void k_attn(
    const ushort* __restrict__ Qb, const ushort* __restrict__ Kb,
    const ushort* __restrict__ VTb, ushort* __restrict__ AOb)
{
    __shared__ ushort smem[29184];
    ushort* Qsm = smem;            // [64][64]  swizzled
    ushort* Ksm = smem + 4096;     // [192][64] swizzled
    ushort* Vts = smem + 16384;    // [64][200] linear ([d][j])
    ushort* Psm = smem;            // [64][200] linear ([q][j]) — overlays Q/K

    const int tid = threadIdx.x;
    const int lane = tid & 63, w = tid >> 6;
    const int g = lane >> 4, c = lane & 15;
    const int s0 = blockIdx.x * 64;
    const int h = blockIdx.y, b = blockIdx.z;
    const int bh = b * 4 + h;
    const size_t base = (size_t)bh * 2048 * 64;

    // --- stage Q (natural), K (natural, row-clamped), Vt (from VTb) ---
#pragma unroll
    for (int it = 0; it < 2; ++it) {
        int ch = it * 256 + tid;                 // 512 chunks of 8 bf16
        int row = ch >> 3, c8 = ch & 7;
        uint4 v = *(const uint4*)&Qb[base + (size_t)(s0 + row) * 64 + c8 * 8];
        *(uint4*)&Qsm[row * 64 + ((c8 * 8) ^ ((row & 7) << 3))] = v;
    }
#pragma unroll
    for (int it = 0; it < 6; ++it) {
        int ch = it * 256 + tid;                 // 1536 chunks
        int row = ch >> 3, c8 = ch & 7;
        int ks = s0 - 64 + row;
        ks = ks < 0 ? 0 : (ks > 2047 ? 2047 : ks);
        uint4 v = *(const uint4*)&Kb[base + (size_t)ks * 64 + c8 * 8];
        *(uint4*)&Ksm[row * 64 + ((c8 * 8) ^ ((row & 7) << 3))] = v;
    }
#pragma unroll
    for (int it = 0; it < 6; ++it) {
        int d = tid >> 2, c8 = it * 4 + (tid & 3);   // 64 d-rows x 24 chunks
        const ushort* vrow = VTb + (size_t)(bh * 64 + d) * 2048;
        uint4 v = *(const uint4*)&vrow[s0 - 64 + c8 * 8];  // OOB edges: finite, P=0
        *(uint4*)&Vts[d * 200 + c8 * 8] = v;
    }
    __syncthreads();

    // --- QK^T: S[q][j], q = w*16+g*4+r, j = ni*16+c (proven A·B^T map) ---
    const int qrow = (w << 4) | c;
    const int swzq = (qrow & 7) << 3;
    short8 a0 = *(const short8*)&Qsm[qrow * 64 + ((g * 8) ^ swzq)];
    short8 a1 = *(const short8*)&Qsm[qrow * 64 + ((32 + g * 8) ^ swzq)];
    f32x4 accS[12];
#pragma unroll
    for (int ni = 0; ni < 12; ++ni) accS[ni] = (f32x4){0.f, 0.f, 0.f, 0.f};
#pragma unroll
    for (int ni = 0; ni < 12; ++ni) {
        int krow = ni * 16 + c;
        int swzk = (krow & 7) << 3;
        short8 b0 = *(const short8*)&Ksm[krow * 64 + ((g * 8) ^ swzk)];
        short8 b1 = *(const short8*)&Ksm[krow * 64 + ((32 + g * 8) ^ swzk)];
        accS[ni] = __builtin_amdgcn_mfma_f32_16x16x32_bf16(a0, b0, accS[ni], 0, 0, 0);
        accS[ni] = __builtin_amdgcn_mfma_f32_16x16x32_bf16(a1, b1, accS[ni], 0, 0, 0);
    }
    __syncthreads();   // barrier #1: all Qsm/Ksm reads done before Psm overwrite

    // --- mask + softmax, fully in-register ---
    float mx[4] = {-1e30f, -1e30f, -1e30f, -1e30f};
#pragma unroll
    for (int ni = 0; ni < 12; ++ni) {
        int j = ni * 16 + c;
        bool inr = (unsigned)(s0 - 64 + j) < 2048u;
#pragma unroll
        for (int r = 0; r < 4; ++r) {
            int qq = (w << 4) + g * 4 + r;
            bool valid = inr && (j >= qq) && (j <= qq + 128);
            float sv = valid ? accS[ni][r] : -1e30f;
            accS[ni][r] = sv;
            mx[r] = fmaxf(mx[r], sv);
        }
    }
#pragma unroll
    for (int hop = 1; hop <= 8; hop <<= 1)
#pragma unroll
        for (int r = 0; r < 4; ++r) mx[r] = fmaxf(mx[r], __shfl_xor(mx[r], hop));
    float L[4] = {0.f, 0.f, 0.f, 0.f};
#pragma unroll
    for (int ni = 0; ni < 12; ++ni)
#pragma unroll
        for (int r = 0; r < 4; ++r) {
            float e = __expf(accS[ni][r] - mx[r]);
            accS[ni][r] = e;
            L[r] += e;
        }
#pragma unroll
    for (int hop = 1; hop <= 8; hop <<= 1)
#pragma unroll
        for (int r = 0; r < 4; ++r) L[r] += __shfl_xor(L[r], hop);
    float inv[4];
#pragma unroll
    for (int r = 0; r < 4; ++r) inv[r] = 1.f / L[r];

    // write P (bf16) to Psm [q][j]
#pragma unroll
    for (int ni = 0; ni < 12; ++ni)
#pragma unroll
        for (int r = 0; r < 4; ++r)
            Psm[((w << 4) + g * 4 + r) * 200 + ni * 16 + c] = bf16r(accS[ni][r]);
    __syncthreads();   // barrier #2

    // --- PV: O[q][d] = sum_j P[q][j] V[j][d]; B = V^T rows (proven map) ---
    f32x4 o[4];
#pragma unroll
    for (int ni = 0; ni < 4; ++ni) o[ni] = (f32x4){0.f, 0.f, 0.f, 0.f};
    const int prow = (w << 4) | c;
#pragma unroll
    for (int jt = 0; jt < 6; ++jt) {
        short8 am = *(const short8*)&Psm[prow * 200 + jt * 32 + g * 8];
#pragma unroll
        for (int ni = 0; ni < 4; ++ni) {
            short8 bn = *(const short8*)&Vts[(ni * 16 + c) * 200 + jt * 32 + g * 8];
            o[ni] = __builtin_amdgcn_mfma_f32_16x16x32_bf16(am, bn, o[ni], 0, 0, 0);
        }
    }
    // epilogue: scale by 1/L (same row ownership as softmax), write bf16
#pragma unroll
    for (int ni = 0; ni < 4; ++ni)
#pragma unroll
        for (int r = 0; r < 4; ++r) {
            int q = (w << 4) + g * 4 + r;
            int d = ni * 16 + c;
            AOb[((size_t)b * 2048 + s0 + q) * 256 + h * 64 + d] =
                bf16r(o[ni][r] * inv[r]);
        }
}

// ---------------------------------------------------------------------------
// K3: out_proj (plain bf16 MFMA) fused with sequence max-pool via atomicMax.
// ---------------------------------------------------------------------------
__global__ __launch_bounds__(256) void k_oproj(
    const ushort* __restrict__ AOb, const float* __restrict__ w,
    const float* __restrict__ bias, unsigned* __restrict__ CTX)
{
    __shared__ ushort Asm[8192];
    __shared__ ushort Bsm[8192];
    const int tid = threadIdx.x;
    const int lane = tid & 63, wv = tid >> 6;
    const int g = lane >> 4, c = lane & 15;
    const int wm = wv >> 1, wn = wv & 1;
    const int m0 = blockIdx.x * 128, n0 = blockIdx.y * 128;

    f32x4 acc[4][4];
#pragma unroll
    for (int mi = 0; mi < 4; ++mi)
#pragma unroll
        for (int ni = 0; ni < 4; ++ni) acc[mi][ni] = (f32x4){0.f, 0.f, 0.f, 0.f};

    for (int ki = 0; ki < 4; ++ki) {
        const int k0 = ki * 64;
#pragma unroll
        for (int it = 0; it < 4; ++it) {
            int ch = it * 256 + tid;            // 1024 chunks of 8 bf16
            int row = ch >> 3, c8 = ch & 7;
            uint4 v = *(const uint4*)&AOb[(size_t)(m0 + row) * 256 + k0 + c8 * 8];
            *(uint4*)&Asm[row * 64 + ((c8 * 8) ^ ((row & 7) << 3))] = v;
        }
#pragma unroll
        for (int it = 0; it < 8; ++it) {
            int ch = it * 256 + tid;
            int row = ch >> 4, f4 = ch & 15;
            float4 x = *(const float4*)&w[(size_t)(n0 + row) * 256 + k0 + f4 * 4];
            uint2 pk = make_uint2(pack2(x.x, x.y), pack2(x.z, x.w));
            *(uint2*)&Bsm[row * 64 + ((f4 * 4) ^ ((row & 7) << 3))] = pk;
        }
        __syncthreads();
#pragma unroll
        for (int ks = 0; ks < 2; ++ks) {
            const int ko = ks * 32 + g * 8;
            short8 am[4], bn[4];
#pragma unroll
            for (int mi = 0; mi < 4; ++mi) {
                int row = wm * 64 + mi * 16 + c;
                am[mi] = *(const short8*)&Asm[row * 64 + (ko ^ ((row & 7) << 3))];
            }
#pragma unroll
            for (int ni = 0; ni < 4; ++ni) {
                int row = wn * 64 + ni * 16 + c;
                bn[ni] = *(const short8*)&Bsm[row * 64 + (ko ^ ((row & 7) << 3))];
            }
#pragma unroll
            for (int mi = 0; mi < 4; ++mi)
#pragma unroll
                for (int ni = 0; ni < 4; ++ni)
                    acc[mi][ni] = __builtin_amdgcn_mfma_f32_16x16x32_bf16(
                        am[mi], bn[ni], acc[mi][ni], 0, 0, 0);
        }
        __syncthreads();
    }

    const int bidx = m0 >> 11;
#pragma unroll
    for (int ni = 0; ni < 4; ++ni) {
        int n = n0 + wn * 64 + ni * 16 + c;
        float mxv = -1e30f;
#pragma unroll
        for (int mi = 0; mi < 4; ++mi)
#pragma unroll
            for (int r = 0; r < 4; ++r) mxv = fmaxf(mxv, acc[mi][ni][r]);
        mxv += bias[n];
        mxv = fmaxf(mxv, __shfl_xor(mxv, 16));
        mxv = fmaxf(mxv, __shfl_xor(mxv, 32));
        if (lane < 16) {
            unsigned bits = __float_as_uint(mxv);
            unsigned en = (bits & 0x80000000u) ? ~bits : (bits | 0x80000000u);
            atomicMax(&CTX[bidx * 256 + n], en);
        }
    }
}

// ---------------------------------------------------------------------------
// K4a: fc1 + leaky_relu (fp32) — proven.
// ---------------------------------------------------------------------------
__global__ __launch_bounds__(256) void k_fc1(
    const unsigned* __restrict__ CTX, const float* __restrict__ w,
    const float* __restrict__ bias, float* __restrict__ H1)
{
    __shared__ float cs[256];
    const int tid = threadIdx.x;
    const int row = blockIdx.x >> 1, half = blockIdx.x & 1;
    unsigned u = CTX[row * 256 + tid];
    unsigned bits = (u & 0x80000000u) ? (u & 0x7fffffffu) : ~u;
    cs[tid] = __uint_as_float(bits);
    __syncthreads();
    const int o = half * 256 + tid;
    float a = bias[o];
#pragma unroll 8
    for (int c4 = 0; c4 < 64; ++c4) {
        float4 w4 = *(const float4*)&w[o * 256 + c4 * 4];
        a = fmaf(w4.x, cs[c4 * 4 + 0], a);
        a = fmaf(w4.y, cs[c4 * 4 + 1], a);
        a = fmaf(w4.z, cs[c4 * 4 + 2], a);
        a = fmaf(w4.w, cs[c4 * 4 + 3], a);
    }
    H1[row * 512 + o] = a > 0.f ? a : 0.01f * a;
}

// ---------------------------------------------------------------------------
// K4b: fc2 + leaky_relu + fc3, single block (fp32) — proven.
// ---------------------------------------------------------------------------
__global__ __launch_bounds__(256) void k_head(
    const float* __restrict__ H1, const float* __restrict__ w2,
    const float* __restrict__ b2, const float* __restrict__ w3,
    const float* __restrict__ b3, float* __restrict__ out)
{
    __shared__ float H1s[8][516];
    __shared__ float H2s[8][260];
    const int tid = threadIdx.x;
    for (int i = tid; i < 4096; i += 256) H1s[i >> 9][i & 511] = H1[i];
    __syncthreads();
    float a2[8];
#pragma unroll
    for (int r = 0; r < 8; ++r) a2[r] = b2[tid];
    for (int c4 = 0; c4 < 128; ++c4) {
        float4 w4 = *(const float4*)&w2[tid * 512 + c4 * 4];
#pragma unroll
        for (int r = 0; r < 8; ++r) {
            a2[r] = fmaf(w4.x, H1s[r][c4 * 4 + 0], a2[r]);
            a2[r] = fmaf(w4.y, H1s[r][c4 * 4 + 1], a2[r]);
            a2[r] = fmaf(w4.z, H1s[r][c4 * 4 + 2], a2[r]);
            a2[r] = fmaf(w4.w, H1s[r][c4 * 4 + 3], a2[r]);
        }
    }
#pragma unroll
    for (int r = 0; r < 8; ++r) {
        float v = a2[r];
        H2s[r][tid] = v > 0.f ? v : 0.01f * v;
    }
    __syncthreads();
    if (tid < 160) {
        int r = tid / 20, o = tid % 20;
        float a = b3[o];
#pragma unroll 8
        for (int c4 = 0; c4 < 64; ++c4) {
            float4 w4 = *(const float4*)&w3[o * 256 + c4 * 4];
            a = fmaf(w4.x, H2s[r][c4 * 4 + 0], a);
            a = fmaf(w4.y, H2s[r][c4 * 4 + 1], a);
            a = fmaf(w4.z, H2s[r][c4 * 4 + 2], a);
            a = fmaf(w4.w, H2s[r][c4 * 4 + 3], a);
        }
        out[tid] = a;
    }
}

// ---------------------------------------------------------------------------
extern "C" void kernel_launch(void* const* d_in, const int* in_sizes, int n_in,
                              void* d_out, int out_size, void* d_ws, size_t ws_size,
                              hipStream_t stream)
{
    (void)in_sizes; (void)n_in; (void)out_size; (void)ws_size;
    const int*   text = (const int*)d_in[0];
    const float* emb  = (const float*)d_in[1];
    const float* ipw  = (const float*)d_in[2];
    const float* ipb  = (const float*)d_in[3];
    const float* opw  = (const float*)d_in[4];
    const float* opb  = (const float*)d_in[5];
    const float* f1w  = (const float*)d_in[6];
    const float* f1b  = (const float*)d_in[7];
    const float* f2w  = (const float*)d_in[8];
    const float* f2b  = (const float*)d_in[9];
    const float* f3w  = (const float*)d_in[10];
    const float* f3b  = (const float*)d_in[11];
    float* out = (float*)d_out;

    // workspace (~33.6 MB; round 3 proved >= 67 MB available)
    unsigned char* w8 = (unsigned char*)d_ws;
    ushort* Qb  = (ushort*)(w8);                    // 8 MiB  [B,H,S,64]
    ushort* Kb  = (ushort*)(w8 + 8388608);          // 8 MiB  [B,H,S,64]
    ushort* VTb = (ushort*)(w8 + 16777216);         // 8 MiB  [B,H,64,S]
    // 64 KiB reserved gap after VTb: OOB window reads stay finite (0xAA poison)
    ushort* AOb = (ushort*)(w8 + 25231360);         // 8 MiB  [B,S,256]
    unsigned* CTX = (unsigned*)(w8 + 33619968);     // 8 KiB
    float* H1 = (float*)(w8 + 33628160);            // 16 KiB

    hipMemsetAsync(CTX, 0, 8192, stream);
    k_qkv<<<dim3(128, 6), 256, 0, stream>>>(text, emb, ipw, ipb, Qb, Kb, VTb);
    k_attn<<<dim3(32, 4, 8), 256, 0, stream>>>(Qb, Kb, VTb, AOb);
    k_oproj<<<dim3(128, 2), 256, 0, stream>>>(AOb, opw, opb, CTX);
    k_fc1<<<16, 256, 0, stream>>>(CTX, f1w, f1b, H1);
    k_head<<<1, 256, 0, stream>>>(H1, f2w, f2b, f3w, f3b, out);
}

// Round 6
// 195.792 us; speedup vs baseline: 1.7718x; 1.1885x over previous
//
#include <hip/hip_runtime.h>
#include <math.h>

typedef __attribute__((ext_vector_type(4))) float f32x4;
typedef __attribute__((ext_vector_type(8))) short short8;

__device__ __forceinline__ ushort bf16r(float f) {
    unsigned u = __float_as_uint(f);
    return (ushort)((u + 0x7FFFu + ((u >> 16) & 1u)) >> 16);
}
__device__ __forceinline__ unsigned pack2(float lo, float hi) {
    return (unsigned)bf16r(lo) | ((unsigned)bf16r(hi) << 16);
}

// async global->LDS, 16B per lane; LDS dest = wave-uniform base + lane*16
#define GLOAD16(gp, lp)                                                        \
    __builtin_amdgcn_global_load_lds(                                          \
        (const __attribute__((address_space(1))) unsigned*)(gp),               \
        (__attribute__((address_space(3))) unsigned*)(lp), 16, 0, 0)

// ---------------------------------------------------------------------------
// K_prep: one pass producing all bf16 operands.
//   Xb  [16384][256] = bf16(emb[text[m]])   (gather hoisted out of k_qkv)
//   Wqb [768][256]   = bf16(in_proj_w)
//   Wob [256][256]   = bf16(out_proj_w)
// ---------------------------------------------------------------------------
__global__ __launch_bounds__(256) void k_prep(
    const int* __restrict__ text, const float* __restrict__ emb,
    const float* __restrict__ ipw, const float* __restrict__ opw,
    ushort* __restrict__ Xb, ushort* __restrict__ Wqb, ushort* __restrict__ Wob)
{
    int t = blockIdx.x * 256 + threadIdx.x;        // 1088 blocks -> 278528 thr
#pragma unroll
    for (int i = t; i < 1114112; i += 278528) {    // chunks of 4 floats
        const float* src; ushort* dst;
        if (i < 1048576) {
            int row = i >> 6, f4 = i & 63;
            int tok = text[row];
            src = &emb[(size_t)tok * 256 + f4 * 4];
            dst = &Xb[(size_t)row * 256 + f4 * 4];
        } else if (i < 1097728) {
            int j = i - 1048576;
            src = &ipw[(size_t)j * 4];
            dst = &Wqb[(size_t)j * 4];
        } else {
            int j = i - 1097728;
            src = &opw[(size_t)j * 4];
            dst = &Wob[(size_t)j * 4];
        }
        float4 x = *(const float4*)src;
        uint2 pk = make_uint2(pack2(x.x, x.y), pack2(x.z, x.w));
        *(uint2*)dst = pk;
    }
}

// ---------------------------------------------------------------------------
// K1: QKV GEMM, bf16 MFMA, global_load_lds direct staging (pre-swizzled
// source, linear LDS dest), 2-phase double-buffered K-loop.
// C[16384,768] = Xb @ Wqb^T + b -> Qb (x1/8), Kb [B,H,S,64]; VTb [B,H,64,S].
// BM=128, BN=128, BK=64, 256 thr (2x2 waves). LDS 64 KiB dyn -> 2 blocks/CU.
// ---------------------------------------------------------------------------
__global__ __launch_bounds__(256) void k_qkv(
    const ushort* __restrict__ Xb, const ushort* __restrict__ Wqb,
    const float* __restrict__ bias,
    ushort* __restrict__ Qb, ushort* __restrict__ Kb, ushort* __restrict__ VTb)
{
    extern __shared__ ushort lds[];    // A[2][8192] @0, B[2][8192] @16384
    const int tid = threadIdx.x;
    const int lane = tid & 63, wv = tid >> 6;
    const int g = lane >> 4, c = lane & 15;
    const int wm = wv >> 1, wn = wv & 1;
    const int m0 = blockIdx.x * 128, n0 = blockIdx.y * 128;

    // per-lane staging geometry: 8 rows per gload, 4 gloads cover 32 rows/wave
    const int lrow = lane >> 3;                   // 0..7
    const int lch  = lane & 7;                    // 16B chunk 0..7

    f32x4 acc[4][4];
#pragma unroll
    for (int mi = 0; mi < 4; ++mi)
#pragma unroll
        for (int ni = 0; ni < 4; ++ni) acc[mi][ni] = (f32x4){0.f, 0.f, 0.f, 0.f};

#define STAGE_QKV(buf, ki)                                                     \
    {                                                                          \
        const int k0_ = (ki) * 64;                                             \
        ushort* Ad_ = lds + (buf) * 8192;                                      \
        ushort* Bd_ = lds + 16384 + (buf) * 8192;                              \
        _Pragma("unroll")                                                      \
        for (int i_ = 0; i_ < 4; ++i_) {                                       \
            int r0_ = wv * 32 + i_ * 8;                                        \
            int row_ = r0_ + lrow;                                             \
            int ch_ = lch ^ (row_ & 7);                                        \
            GLOAD16(&Xb[(size_t)(m0 + row_) * 256 + k0_ + ch_ * 8],            \
                    &Ad_[r0_ * 64]);                                           \
            GLOAD16(&Wqb[(size_t)(n0 + row_) * 256 + k0_ + ch_ * 8],           \
                    &Bd_[r0_ * 64]);                                           \
        }                                                                      \
    }

    STAGE_QKV(0, 0)
    __syncthreads();
    int cur = 0;
    for (int ki = 0; ki < 4; ++ki) {
        if (ki < 3) STAGE_QKV(cur ^ 1, ki + 1)
        const ushort* A = lds + cur * 8192;
        const ushort* B = lds + 16384 + cur * 8192;
#pragma unroll
        for (int ks = 0; ks < 2; ++ks) {
            const int ko = ks * 32 + g * 8;
            short8 am[4], bn[4];
#pragma unroll
            for (int mi = 0; mi < 4; ++mi) {
                int row = wm * 64 + mi * 16 + c;
                am[mi] = *(const short8*)&A[row * 64 + (ko ^ ((row & 7) << 3))];
            }
#pragma unroll
            for (int ni = 0; ni < 4; ++ni) {
                int row = wn * 64 + ni * 16 + c;
                bn[ni] = *(const short8*)&B[row * 64 + (ko ^ ((row & 7) << 3))];
            }
#pragma unroll
            for (int mi = 0; mi < 4; ++mi)
#pragma unroll
                for (int ni = 0; ni < 4; ++ni)
                    acc[mi][ni] = __builtin_amdgcn_mfma_f32_16x16x32_bf16(
                        am[mi], bn[ni], acc[mi][ni], 0, 0, 0);
        }
        __syncthreads();   // drains vmcnt (next-stage loads) + lgkm, syncs swap
        cur ^= 1;
    }

    // epilogue (proven): bias, q-scale, scatter; V transposed
    const int sec = n0 >> 8;                    // 0=Q, 1=K, 2=V
    if (sec < 2) {
        ushort* dst = sec == 0 ? Qb : Kb;
        const float scale = sec == 0 ? 0.125f : 1.0f;
#pragma unroll
        for (int ni = 0; ni < 4; ++ni) {
            int n = n0 + wn * 64 + ni * 16 + c;
            float bv = bias[n];
            int h = (n >> 6) & 3, d = n & 63;
#pragma unroll
            for (int mi = 0; mi < 4; ++mi)
#pragma unroll
                for (int r = 0; r < 4; ++r) {
                    int m = m0 + wm * 64 + mi * 16 + g * 4 + r;
                    int bb = m >> 11, s = m & 2047;
                    dst[(size_t)((bb * 4 + h) * 2048 + s) * 64 + d] =
                        bf16r((acc[mi][ni][r] + bv) * scale);
                }
        }
    } else {
#pragma unroll
        for (int ni = 0; ni < 4; ++ni) {
            int n = n0 + wn * 64 + ni * 16 + c;
            float bv = bias[n];
            int h = (n >> 6) & 3, d = n & 63;
#pragma unroll
            for (int mi = 0; mi < 4; ++mi) {
                int sb = m0 + wm * 64 + mi * 16 + g * 4;
                int bb = sb >> 11, s = sb & 2047;
                float v0 = acc[mi][ni][0] + bv, v1 = acc[mi][ni][1] + bv;
                float v2 = acc[mi][ni][2] + bv, v3 = acc[mi][ni][3] + bv;
                uint2 pk = make_uint2(pack2(v0, v1), pack2(v2, v3));
                *(uint2*)&VTb[(size_t)((bb * 4 + h) * 64 + d) * 2048 + s] = pk;
            }
        }
    }
}

// ---------------------------------------------------------------------------
// K2: banded attention — round-5 verbatim (passed, bit-identical).
// ---------------------------------------------------------------------------
__global__ __launch_bounds__(256) void k_attn(
    const ushort* __restrict__ Qb, const ushort* __restrict__ Kb,
    const ushort* __restrict__ VTb, ushort* __restrict__ AOb)
{
    __shared__ ushort smem[29184];
    ushort* Qsm = smem;            // [64][64]  swizzled
    ushort* Ksm = smem + 4096;     // [192][64] swizzled
    ushort* Vts = smem + 16384;    // [64][200] linear ([d][j])
    ushort* Psm = smem;            // [64][200] linear ([q][j]) — overlays Q/K

    const int tid = threadIdx.x;
    const int lane = tid & 63, w = tid >> 6;
    const int g = lane >> 4, c = lane & 15;
    const int s0 = blockIdx.x * 64;
    const int h = blockIdx.y, b = blockIdx.z;
    const int bh = b * 4 + h;
    const size_t base = (size_t)bh * 2048 * 64;

#pragma unroll
    for (int it = 0; it < 2; ++it) {
        int ch = it * 256 + tid;
        int row = ch >> 3, c8 = ch & 7;
        uint4 v = *(const uint4*)&Qb[base + (size_t)(s0 + row) * 64 + c8 * 8];
        *(uint4*)&Qsm[row * 64 + ((c8 * 8) ^ ((row & 7) << 3))] = v;
    }
#pragma unroll
    for (int it = 0; it < 6; ++it) {
        int ch = it * 256 + tid;
        int row = ch >> 3, c8 = ch & 7;
        int ks = s0 - 64 + row;
        ks = ks < 0 ? 0 : (ks > 2047 ? 2047 : ks);
        uint4 v = *(const uint4*)&Kb[base + (size_t)ks * 64 + c8 * 8];
        *(uint4*)&Ksm[row * 64 + ((c8 * 8) ^ ((row & 7) << 3))] = v;
    }
#pragma unroll
    for (int it = 0; it < 6; ++it) {
        int d = tid >> 2, c8 = it * 4 + (tid & 3);
        const ushort* vrow = VTb + (size_t)(bh * 64 + d) * 2048;
        uint4 v = *(const uint4*)&vrow[s0 - 64 + c8 * 8];  // OOB edges finite, P=0
        *(uint4*)&Vts[d * 200 + c8 * 8] = v;
    }
    __syncthreads();

    const int qrow = (w << 4) | c;
    const int swzq = (qrow & 7) << 3;
    short8 a0 = *(const short8*)&Qsm[qrow * 64 + ((g * 8) ^ swzq)];
    short8 a1 = *(const short8*)&Qsm[qrow * 64 + ((32 + g * 8) ^ swzq)];
    f32x4 accS[12];
#pragma unroll
    for (int ni = 0; ni < 12; ++ni) accS[ni] = (f32x4){0.f, 0.f, 0.f, 0.f};
#pragma unroll
    for (int ni = 0; ni < 12; ++ni) {
        int krow = ni * 16 + c;
        int swzk = (krow & 7) << 3;
        short8 b0 = *(const short8*)&Ksm[krow * 64 + ((g * 8) ^ swzk)];
        short8 b1 = *(const short8*)&Ksm[krow * 64 + ((32 + g * 8) ^ swzk)];
        accS[ni] = __builtin_amdgcn_mfma_f32_16x16x32_bf16(a0, b0, accS[ni], 0, 0, 0);
        accS[ni] = __builtin_amdgcn_mfma_f32_16x16x32_bf16(a1, b1, accS[ni], 0, 0, 0);
    }
    __syncthreads();

    float mx[4] = {-1e30f, -1e30f, -1e30f, -1e30f};
#pragma unroll
    for (int ni = 0; ni < 12; ++ni) {
        int j = ni * 16 + c;
        bool inr = (unsigned)(s0 - 64 + j) < 2048u;
#pragma unroll
        for (int r = 0; r < 4; ++r) {
            int qq = (w << 4) + g * 4 + r;
            bool valid = inr && (j >= qq) && (j <= qq + 128);
            float sv = valid ? accS[ni][r] : -1e30f;
            accS[ni][r] = sv;
            mx[r] = fmaxf(mx[r], sv);
        }
    }
#pragma unroll
    for (int hop = 1; hop <= 8; hop <<= 1)
#pragma unroll
        for (int r = 0; r < 4; ++r) mx[r] = fmaxf(mx[r], __shfl_xor(mx[r], hop));
    float L[4] = {0.f, 0.f, 0.f, 0.f};
#pragma unroll
    for (int ni = 0; ni < 12; ++ni)
#pragma unroll
        for (int r = 0; r < 4; ++r) {
            float e = __expf(accS[ni][r] - mx[r]);
            accS[ni][r] = e;
            L[r] += e;
        }
#pragma unroll
    for (int hop = 1; hop <= 8; hop <<= 1)
#pragma unroll
        for (int r = 0; r < 4; ++r) L[r] += __shfl_xor(L[r], hop);
    float inv[4];
#pragma unroll
    for (int r = 0; r < 4; ++r) inv[r] = 1.f / L[r];

#pragma unroll
    for (int ni = 0; ni < 12; ++ni)
#pragma unroll
        for (int r = 0; r < 4; ++r)
            Psm[((w << 4) + g * 4 + r) * 200 + ni * 16 + c] = bf16r(accS[ni][r]);
    __syncthreads();

    f32x4 o[4];
#pragma unroll
    for (int ni = 0; ni < 4; ++ni) o[ni] = (f32x4){0.f, 0.f, 0.f, 0.f};
    const int prow = (w << 4) | c;
#pragma unroll
    for (int jt = 0; jt < 6; ++jt) {
        short8 am = *(const short8*)&Psm[prow * 200 + jt * 32 + g * 8];
#pragma unroll
        for (int ni = 0; ni < 4; ++ni) {
            short8 bn = *(const short8*)&Vts[(ni * 16 + c) * 200 + jt * 32 + g * 8];
            o[ni] = __builtin_amdgcn_mfma_f32_16x16x32_bf16(am, bn, o[ni], 0, 0, 0);
        }
    }
#pragma unroll
    for (int ni = 0; ni < 4; ++ni)
#pragma unroll
        for (int r = 0; r < 4; ++r) {
            int q = (w << 4) + g * 4 + r;
            int d = ni * 16 + c;
            AOb[((size_t)b * 2048 + s0 + q) * 256 + h * 64 + d] =
                bf16r(o[ni][r] * inv[r]);
        }
}

// ---------------------------------------------------------------------------
// K3: out_proj GEMM + max-pool, same gload_lds 2-phase structure as k_qkv.
// ---------------------------------------------------------------------------
__global__ __launch_bounds__(256) void k_oproj(
    const ushort* __restrict__ AOb, const ushort* __restrict__ Wob,
    const float* __restrict__ bias, unsigned* __restrict__ CTX)
{
    extern __shared__ ushort lds[];
    const int tid = threadIdx.x;
    const int lane = tid & 63, wv = tid >> 6;
    const int g = lane >> 4, c = lane & 15;
    const int wm = wv >> 1, wn = wv & 1;
    const int m0 = blockIdx.x * 128, n0 = blockIdx.y * 128;
    const int lrow = lane >> 3, lch = lane & 7;

    f32x4 acc[4][4];
#pragma unroll
    for (int mi = 0; mi < 4; ++mi)
#pragma unroll
        for (int ni = 0; ni < 4; ++ni) acc[mi][ni] = (f32x4){0.f, 0.f, 0.f, 0.f};

#define STAGE_OP(buf, ki)                                                      \
    {                                                                          \
        const int k0_ = (ki) * 64;                                             \
        ushort* Ad_ = lds + (buf) * 8192;                                      \
        ushort* Bd_ = lds + 16384 + (buf) * 8192;                              \
        _Pragma("unroll")                                                      \
        for (int i_ = 0; i_ < 4; ++i_) {                                       \
            int r0_ = wv * 32 + i_ * 8;                                        \
            int row_ = r0_ + lrow;                                             \
            int ch_ = lch ^ (row_ & 7);                                        \
            GLOAD16(&AOb[(size_t)(m0 + row_) * 256 + k0_ + ch_ * 8],           \
                    &Ad_[r0_ * 64]);                                           \
            GLOAD16(&Wob[(size_t)(n0 + row_) * 256 + k0_ + ch_ * 8],           \
                    &Bd_[r0_ * 64]);                                           \
        }                                                                      \
    }

    STAGE_OP(0, 0)
    __syncthreads();
    int cur = 0;
    for (int ki = 0; ki < 4; ++ki) {
        if (ki < 3) STAGE_OP(cur ^ 1, ki + 1)
        const ushort* A = lds + cur * 8192;
        const ushort* B = lds + 16384 + cur * 8192;
#pragma unroll
        for (int ks = 0; ks < 2; ++ks) {
            const int ko = ks * 32 + g * 8;
            short8 am[4], bn[4];
#pragma unroll
            for (int mi = 0; mi < 4; ++mi) {
                int row = wm * 64 + mi * 16 + c;
                am[mi] = *(const short8*)&A[row * 64 + (ko ^ ((row & 7) << 3))];
            }
#pragma unroll
            for (int ni = 0; ni < 4; ++ni) {
                int row = wn * 64 + ni * 16 + c;
                bn[ni] = *(const short8*)&B[row * 64 + (ko ^ ((row & 7) << 3))];
            }
#pragma unroll
            for (int mi = 0; mi < 4; ++mi)
#pragma unroll
                for (int ni = 0; ni < 4; ++ni)
                    acc[mi][ni] = __builtin_amdgcn_mfma_f32_16x16x32_bf16(
                        am[mi], bn[ni], acc[mi][ni], 0, 0, 0);
        }
        __syncthreads();
        cur ^= 1;
    }

    const int bidx = m0 >> 11;
#pragma unroll
    for (int ni = 0; ni < 4; ++ni) {
        int n = n0 + wn * 64 + ni * 16 + c;
        float mxv = -1e30f;
#pragma unroll
        for (int mi = 0; mi < 4; ++mi)
#pragma unroll
            for (int r = 0; r < 4; ++r) mxv = fmaxf(mxv, acc[mi][ni][r]);
        mxv += bias[n];
        mxv = fmaxf(mxv, __shfl_xor(mxv, 16));
        mxv = fmaxf(mxv, __shfl_xor(mxv, 32));
        if (lane < 16) {
            unsigned bits = __float_as_uint(mxv);
            unsigned en = (bits & 0x80000000u) ? ~bits : (bits | 0x80000000u);
            atomicMax(&CTX[bidx * 256 + n], en);
        }
    }
}

// ---------------------------------------------------------------------------
// K4a: fc1 + leaky_relu (fp32) — proven.
// ---------------------------------------------------------------------------
__global__ __launch_bounds__(256) void k_fc1(
    const unsigned* __restrict__ CTX, const float* __restrict__ w,
    const float* __restrict__ bias, float* __restrict__ H1)
{
    __shared__ float cs[256];
    const int tid = threadIdx.x;
    const int row = blockIdx.x >> 1, half = blockIdx.x & 1;
    unsigned u = CTX[row * 256 + tid];
    unsigned bits = (u & 0x80000000u) ? (u & 0x7fffffffu) : ~u;
    cs[tid] = __uint_as_float(bits);
    __syncthreads();
    const int o = half * 256 + tid;
    float a = bias[o];
#pragma unroll 8
    for (int c4 = 0; c4 < 64; ++c4) {
        float4 w4 = *(const float4*)&w[o * 256 + c4 * 4];
        a = fmaf(w4.x, cs[c4 * 4 + 0], a);
        a = fmaf(w4.y, cs[c4 * 4 + 1], a);
        a = fmaf(w4.z, cs[c4 * 4 + 2], a);
        a = fmaf(w4.w, cs[c4 * 4 + 3], a);
    }
    H1[row * 512 + o] = a > 0.f ? a : 0.01f * a;
}

// ---------------------------------------------------------------------------
// K4b: fc2 + leaky_relu + fc3, single block (fp32) — proven.
// ---------------------------------------------------------------------------
__global__ __launch_bounds__(256) void k_head(
    const float* __restrict__ H1, const float* __restrict__ w2,
    const float* __restrict__ b2, const float* __restrict__ w3,
    const float* __restrict__ b3, float* __restrict__ out)
{
    __shared__ float H1s[8][516];
    __shared__ float H2s[8][260];
    const int tid = threadIdx.x;
    for (int i = tid; i < 4096; i += 256) H1s[i >> 9][i & 511] = H1[i];
    __syncthreads();
    float a2[8];
#pragma unroll
    for (int r = 0; r < 8; ++r) a2[r] = b2[tid];
    for (int c4 = 0; c4 < 128; ++c4) {
        float4 w4 = *(const float4*)&w2[tid * 512 + c4 * 4];
#pragma unroll
        for (int r = 0; r < 8; ++r) {
            a2[r] = fmaf(w4.x, H1s[r][c4 * 4 + 0], a2[r]);
            a2[r] = fmaf(w4.y, H1s[r][c4 * 4 + 1], a2[r]);
            a2[r] = fmaf(w4.z, H1s[r][c4 * 4 + 2], a2[r]);
            a2[r] = fmaf(w4.w, H1s[r][c4 * 4 + 3], a2[r]);
        }
    }
#pragma unroll
    for (int r = 0; r < 8; ++r) {
        float v = a2[r];
        H2s[r][tid] = v > 0.f ? v : 0.01f * v;
    }
    __syncthreads();
    if (tid < 160) {
        int r = tid / 20, o = tid % 20;
        float a = b3[o];
#pragma unroll 8
        for (int c4 = 0; c4 < 64; ++c4) {
            float4 w4 = *(const float4*)&w3[o * 256 + c4 * 4];
            a = fmaf(w4.x, H2s[r][c4 * 4 + 0], a);
            a = fmaf(w4.y, H2s[r][c4 * 4 + 1], a);
            a = fmaf(w4.z, H2s[r][c4 * 4 + 2], a);
            a = fmaf(w4.w, H2s[r][c4 * 4 + 3], a);
        }
        out[tid] = a;
    }
}

// ---------------------------------------------------------------------------
extern "C" void kernel_launch(void* const* d_in, const int* in_sizes, int n_in,
                              void* d_out, int out_size, void* d_ws, size_t ws_size,
                              hipStream_t stream)
{
    (void)in_sizes; (void)n_in; (void)out_size; (void)ws_size;
    const int*   text = (const int*)d_in[0];
    const float* emb  = (const float*)d_in[1];
    const float* ipw  = (const float*)d_in[2];
    const float* ipb  = (const float*)d_in[3];
    const float* opw  = (const float*)d_in[4];
    const float* opb  = (const float*)d_in[5];
    const float* f1w  = (const float*)d_in[6];
    const float* f1b  = (const float*)d_in[7];
    const float* f2w  = (const float*)d_in[8];
    const float* f2b  = (const float*)d_in[9];
    const float* f3w  = (const float*)d_in[10];
    const float* f3b  = (const float*)d_in[11];
    float* out = (float*)d_out;

    // workspace ~42.6 MB (67 MB proven available)
    unsigned char* w8 = (unsigned char*)d_ws;
    ushort* Xb  = (ushort*)(w8);                    // 8 MiB [16384][256]
    ushort* Qb  = (ushort*)(w8 + 8388608);          // 8 MiB [B,H,S,64]
    ushort* Kb  = (ushort*)(w8 + 16777216);         // 8 MiB [B,H,S,64]
    ushort* VTb = (ushort*)(w8 + 25165824);         // 8 MiB [B,H,64,S]
    // 64 KiB gap: OOB window reads past VTb stay finite
    ushort* AOb = (ushort*)(w8 + 33619968);         // 8 MiB [B,S,256]
    ushort* Wqb = (ushort*)(w8 + 42008576);         // 384 KiB
    ushort* Wob = (ushort*)(w8 + 42401792);         // 128 KiB
    unsigned* CTX = (unsigned*)(w8 + 42532864);     // 8 KiB
    float* H1 = (float*)(w8 + 42541056);            // 16 KiB

    hipFuncSetAttribute((const void*)k_qkv,
                        hipFuncAttributeMaxDynamicSharedMemorySize, 65536);
    hipFuncSetAttribute((const void*)k_oproj,
                        hipFuncAttributeMaxDynamicSharedMemorySize, 65536);

    hipMemsetAsync(CTX, 0, 8192, stream);
    k_prep<<<1088, 256, 0, stream>>>(text, emb, ipw, opw, Xb, Wqb, Wob);
    k_qkv<<<dim3(128, 6), 256, 65536, stream>>>(Xb, Wqb, ipb, Qb, Kb, VTb);
    k_attn<<<dim3(32, 4, 8), 256, 0, stream>>>(Qb, Kb, VTb, AOb);
    k_oproj<<<dim3(128, 2), 256, 65536, stream>>>(AOb, Wob, opb, CTX);
    k_fc1<<<16, 256, 0, stream>>>(CTX, f1w, f1b, H1);
    k_head<<<1, 256, 0, stream>>>(H1, f2w, f2b, f3w, f3b, out);
}

// Round 7
// 161.729 us; speedup vs baseline: 2.1450x; 1.2106x over previous
//
#include <hip/hip_runtime.h>
#include <math.h>

typedef __attribute__((ext_vector_type(4))) float f32x4;
typedef __attribute__((ext_vector_type(8))) short short8;

__device__ __forceinline__ ushort bf16r(float f) {
    unsigned u = __float_as_uint(f);
    return (ushort)((u + 0x7FFFu + ((u >> 16) & 1u)) >> 16);
}
__device__ __forceinline__ unsigned pack2(float lo, float hi) {
    return (unsigned)bf16r(lo) | ((unsigned)bf16r(hi) << 16);
}

// async global->LDS, 16B per lane; LDS dest = wave-uniform base + lane*16
#define GLOAD16(gp, lp)                                                        \
    __builtin_amdgcn_global_load_lds(                                          \
        (const __attribute__((address_space(1))) unsigned*)(gp),               \
        (__attribute__((address_space(3))) unsigned*)(lp), 16, 0, 0)

// ---------------------------------------------------------------------------
// K_prep: one pass producing all bf16 operands.
// ---------------------------------------------------------------------------
__global__ __launch_bounds__(256) void k_prep(
    const int* __restrict__ text, const float* __restrict__ emb,
    const float* __restrict__ ipw, const float* __restrict__ opw,
    ushort* __restrict__ Xb, ushort* __restrict__ Wqb, ushort* __restrict__ Wob)
{
    int t = blockIdx.x * 256 + threadIdx.x;        // 1088 blocks -> 278528 thr
#pragma unroll
    for (int i = t; i < 1114112; i += 278528) {    // chunks of 4 floats
        const float* src; ushort* dst;
        if (i < 1048576) {
            int row = i >> 6, f4 = i & 63;
            int tok = text[row];
            src = &emb[(size_t)tok * 256 + f4 * 4];
            dst = &Xb[(size_t)row * 256 + f4 * 4];
        } else if (i < 1097728) {
            int j = i - 1048576;
            src = &ipw[(size_t)j * 4];
            dst = &Wqb[(size_t)j * 4];
        } else {
            int j = i - 1097728;
            src = &opw[(size_t)j * 4];
            dst = &Wob[(size_t)j * 4];
        }
        float4 x = *(const float4*)src;
        uint2 pk = make_uint2(pack2(x.x, x.y), pack2(x.z, x.w));
        *(uint2*)dst = pk;
    }
}

// ---------------------------------------------------------------------------
// K1: QKV GEMM, bf16 MFMA, global_load_lds staging, 2-phase double buffer.
// ---------------------------------------------------------------------------
__global__ __launch_bounds__(256) void k_qkv(
    const ushort* __restrict__ Xb, const ushort* __restrict__ Wqb,
    const float* __restrict__ bias,
    ushort* __restrict__ Qb, ushort* __restrict__ Kb, ushort* __restrict__ VTb)
{
    extern __shared__ ushort lds[];    // A[2][8192] @0, B[2][8192] @16384
    const int tid = threadIdx.x;
    const int lane = tid & 63, wv = tid >> 6;
    const int g = lane >> 4, c = lane & 15;
    const int wm = wv >> 1, wn = wv & 1;
    const int m0 = blockIdx.x * 128, n0 = blockIdx.y * 128;
    const int lrow = lane >> 3;                   // 0..7
    const int lch  = lane & 7;                    // 16B chunk 0..7

    f32x4 acc[4][4];
#pragma unroll
    for (int mi = 0; mi < 4; ++mi)
#pragma unroll
        for (int ni = 0; ni < 4; ++ni) acc[mi][ni] = (f32x4){0.f, 0.f, 0.f, 0.f};

#define STAGE_QKV(buf, ki)                                                     \
    {                                                                          \
        const int k0_ = (ki) * 64;                                             \
        ushort* Ad_ = lds + (buf) * 8192;                                      \
        ushort* Bd_ = lds + 16384 + (buf) * 8192;                              \
        _Pragma("unroll")                                                      \
        for (int i_ = 0; i_ < 4; ++i_) {                                       \
            int r0_ = wv * 32 + i_ * 8;                                        \
            int row_ = r0_ + lrow;                                             \
            int ch_ = lch ^ (row_ & 7);                                        \
            GLOAD16(&Xb[(size_t)(m0 + row_) * 256 + k0_ + ch_ * 8],            \
                    &Ad_[r0_ * 64]);                                           \
            GLOAD16(&Wqb[(size_t)(n0 + row_) * 256 + k0_ + ch_ * 8],           \
                    &Bd_[r0_ * 64]);                                           \
        }                                                                      \
    }

    STAGE_QKV(0, 0)
    __syncthreads();
    int cur = 0;
    for (int ki = 0; ki < 4; ++ki) {
        if (ki < 3) STAGE_QKV(cur ^ 1, ki + 1)
        const ushort* A = lds + cur * 8192;
        const ushort* B = lds + 16384 + cur * 8192;
#pragma unroll
        for (int ks = 0; ks < 2; ++ks) {
            const int ko = ks * 32 + g * 8;
            short8 am[4], bn[4];
#pragma unroll
            for (int mi = 0; mi < 4; ++mi) {
                int row = wm * 64 + mi * 16 + c;
                am[mi] = *(const short8*)&A[row * 64 + (ko ^ ((row & 7) << 3))];
            }
#pragma unroll
            for (int ni = 0; ni < 4; ++ni) {
                int row = wn * 64 + ni * 16 + c;
                bn[ni] = *(const short8*)&B[row * 64 + (ko ^ ((row & 7) << 3))];
            }
#pragma unroll
            for (int mi = 0; mi < 4; ++mi)
#pragma unroll
                for (int ni = 0; ni < 4; ++ni)
                    acc[mi][ni] = __builtin_amdgcn_mfma_f32_16x16x32_bf16(
                        am[mi], bn[ni], acc[mi][ni], 0, 0, 0);
        }
        __syncthreads();
        cur ^= 1;
    }

    const int sec = n0 >> 8;                    // 0=Q, 1=K, 2=V
    if (sec < 2) {
        ushort* dst = sec == 0 ? Qb : Kb;
        const float scale = sec == 0 ? 0.125f : 1.0f;
#pragma unroll
        for (int ni = 0; ni < 4; ++ni) {
            int n = n0 + wn * 64 + ni * 16 + c;
            float bv = bias[n];
            int h = (n >> 6) & 3, d = n & 63;
#pragma unroll
            for (int mi = 0; mi < 4; ++mi)
#pragma unroll
                for (int r = 0; r < 4; ++r) {
                    int m = m0 + wm * 64 + mi * 16 + g * 4 + r;
                    int bb = m >> 11, s = m & 2047;
                    dst[(size_t)((bb * 4 + h) * 2048 + s) * 64 + d] =
                        bf16r((acc[mi][ni][r] + bv) * scale);
                }
        }
    } else {
#pragma unroll
        for (int ni = 0; ni < 4; ++ni) {
            int n = n0 + wn * 64 + ni * 16 + c;
            float bv = bias[n];
            int h = (n >> 6) & 3, d = n & 63;
#pragma unroll
            for (int mi = 0; mi < 4; ++mi) {
                int sb = m0 + wm * 64 + mi * 16 + g * 4;
                int bb = sb >> 11, s = sb & 2047;
                float v0 = acc[mi][ni][0] + bv, v1 = acc[mi][ni][1] + bv;
                float v2 = acc[mi][ni][2] + bv, v3 = acc[mi][ni][3] + bv;
                uint2 pk = make_uint2(pack2(v0, v1), pack2(v2, v3));
                *(uint2*)&VTb[(size_t)((bb * 4 + h) * 64 + d) * 2048 + s] = pk;
            }
        }
    }
}

// ---------------------------------------------------------------------------
// K2: banded attention — round-5/6 verbatim (passed).
// ---------------------------------------------------------------------------
__global__ __launch_bounds__(256) void k_attn(
    const ushort* __restrict__ Qb, const ushort* __restrict__ Kb,
    const ushort* __restrict__ VTb, ushort* __restrict__ AOb)
{
    __shared__ ushort smem[29184];
    ushort* Qsm = smem;            // [64][64]  swizzled
    ushort* Ksm = smem + 4096;     // [192][64] swizzled
    ushort* Vts = smem + 16384;    // [64][200] linear ([d][j])
    ushort* Psm = smem;            // [64][200] linear ([q][j]) — overlays Q/K

    const int tid = threadIdx.x;
    const int lane = tid & 63, w = tid >> 6;
    const int g = lane >> 4, c = lane & 15;
    const int s0 = blockIdx.x * 64;
    const int h = blockIdx.y, b = blockIdx.z;
    const int bh = b * 4 + h;
    const size_t base = (size_t)bh * 2048 * 64;

#pragma unroll
    for (int it = 0; it < 2; ++it) {
        int ch = it * 256 + tid;
        int row = ch >> 3, c8 = ch & 7;
        uint4 v = *(const uint4*)&Qb[base + (size_t)(s0 + row) * 64 + c8 * 8];
        *(uint4*)&Qsm[row * 64 + ((c8 * 8) ^ ((row & 7) << 3))] = v;
    }
#pragma unroll
    for (int it = 0; it < 6; ++it) {
        int ch = it * 256 + tid;
        int row = ch >> 3, c8 = ch & 7;
        int ks = s0 - 64 + row;
        ks = ks < 0 ? 0 : (ks > 2047 ? 2047 : ks);
        uint4 v = *(const uint4*)&Kb[base + (size_t)ks * 64 + c8 * 8];
        *(uint4*)&Ksm[row * 64 + ((c8 * 8) ^ ((row & 7) << 3))] = v;
    }
#pragma unroll
    for (int it = 0; it < 6; ++it) {
        int d = tid >> 2, c8 = it * 4 + (tid & 3);
        const ushort* vrow = VTb + (size_t)(bh * 64 + d) * 2048;
        uint4 v = *(const uint4*)&vrow[s0 - 64 + c8 * 8];  // OOB edges finite, P=0
        *(uint4*)&Vts[d * 200 + c8 * 8] = v;
    }
    __syncthreads();

    const int qrow = (w << 4) | c;
    const int swzq = (qrow & 7) << 3;
    short8 a0 = *(const short8*)&Qsm[qrow * 64 + ((g * 8) ^ swzq)];
    short8 a1 = *(const short8*)&Qsm[qrow * 64 + ((32 + g * 8) ^ swzq)];
    f32x4 accS[12];
#pragma unroll
    for (int ni = 0; ni < 12; ++ni) accS[ni] = (f32x4){0.f, 0.f, 0.f, 0.f};
#pragma unroll
    for (int ni = 0; ni < 12; ++ni) {
        int krow = ni * 16 + c;
        int swzk = (krow & 7) << 3;
        short8 b0 = *(const short8*)&Ksm[krow * 64 + ((g * 8) ^ swzk)];
        short8 b1 = *(const short8*)&Ksm[krow * 64 + ((32 + g * 8) ^ swzk)];
        accS[ni] = __builtin_amdgcn_mfma_f32_16x16x32_bf16(a0, b0, accS[ni], 0, 0, 0);
        accS[ni] = __builtin_amdgcn_mfma_f32_16x16x32_bf16(a1, b1, accS[ni], 0, 0, 0);
    }
    __syncthreads();

    float mx[4] = {-1e30f, -1e30f, -1e30f, -1e30f};
#pragma unroll
    for (int ni = 0; ni < 12; ++ni) {
        int j = ni * 16 + c;
        bool inr = (unsigned)(s0 - 64 + j) < 2048u;
#pragma unroll
        for (int r = 0; r < 4; ++r) {
            int qq = (w << 4) + g * 4 + r;
            bool valid = inr && (j >= qq) && (j <= qq + 128);
            float sv = valid ? accS[ni][r] : -1e30f;
            accS[ni][r] = sv;
            mx[r] = fmaxf(mx[r], sv);
        }
    }
#pragma unroll
    for (int hop = 1; hop <= 8; hop <<= 1)
#pragma unroll
        for (int r = 0; r < 4; ++r) mx[r] = fmaxf(mx[r], __shfl_xor(mx[r], hop));
    float L[4] = {0.f, 0.f, 0.f, 0.f};
#pragma unroll
    for (int ni = 0; ni < 12; ++ni)
#pragma unroll
        for (int r = 0; r < 4; ++r) {
            float e = __expf(accS[ni][r] - mx[r]);
            accS[ni][r] = e;
            L[r] += e;
        }
#pragma unroll
    for (int hop = 1; hop <= 8; hop <<= 1)
#pragma unroll
        for (int r = 0; r < 4; ++r) L[r] += __shfl_xor(L[r], hop);
    float inv[4];
#pragma unroll
    for (int r = 0; r < 4; ++r) inv[r] = 1.f / L[r];

#pragma unroll
    for (int ni = 0; ni < 12; ++ni)
#pragma unroll
        for (int r = 0; r < 4; ++r)
            Psm[((w << 4) + g * 4 + r) * 200 + ni * 16 + c] = bf16r(accS[ni][r]);
    __syncthreads();

    f32x4 o[4];
#pragma unroll
    for (int ni = 0; ni < 4; ++ni) o[ni] = (f32x4){0.f, 0.f, 0.f, 0.f};
    const int prow = (w << 4) | c;
#pragma unroll
    for (int jt = 0; jt < 6; ++jt) {
        short8 am = *(const short8*)&Psm[prow * 200 + jt * 32 + g * 8];
#pragma unroll
        for (int ni = 0; ni < 4; ++ni) {
            short8 bn = *(const short8*)&Vts[(ni * 16 + c) * 200 + jt * 32 + g * 8];
            o[ni] = __builtin_amdgcn_mfma_f32_16x16x32_bf16(am, bn, o[ni], 0, 0, 0);
        }
    }
#pragma unroll
    for (int ni = 0; ni < 4; ++ni)
#pragma unroll
        for (int r = 0; r < 4; ++r) {
            int q = (w << 4) + g * 4 + r;
            int d = ni * 16 + c;
            AOb[((size_t)b * 2048 + s0 + q) * 256 + h * 64 + d] =
                bf16r(o[ni][r] * inv[r]);
        }
}

// ---------------------------------------------------------------------------
// K3: out_proj GEMM + max-pool — round-6 verbatim.
// ---------------------------------------------------------------------------
__global__ __launch_bounds__(256) void k_oproj(
    const ushort* __restrict__ AOb, const ushort* __restrict__ Wob,
    const float* __restrict__ bias, unsigned* __restrict__ CTX)
{
    extern __shared__ ushort lds[];
    const int tid = threadIdx.x;
    const int lane = tid & 63, wv = tid >> 6;
    const int g = lane >> 4, c = lane & 15;
    const int wm = wv >> 1, wn = wv & 1;
    const int m0 = blockIdx.x * 128, n0 = blockIdx.y * 128;
    const int lrow = lane >> 3, lch = lane & 7;

    f32x4 acc[4][4];
#pragma unroll
    for (int mi = 0; mi < 4; ++mi)
#pragma unroll
        for (int ni = 0; ni < 4; ++ni) acc[mi][ni] = (f32x4){0.f, 0.f, 0.f, 0.f};

#define STAGE_OP(buf, ki)                                                      \
    {                                                                          \
        const int k0_ = (ki) * 64;                                             \
        ushort* Ad_ = lds + (buf) * 8192;                                      \
        ushort* Bd_ = lds + 16384 + (buf) * 8192;                              \
        _Pragma("unroll")                                                      \
        for (int i_ = 0; i_ < 4; ++i_) {                                       \
            int r0_ = wv * 32 + i_ * 8;                                        \
            int row_ = r0_ + lrow;                                             \
            int ch_ = lch ^ (row_ & 7);                                        \
            GLOAD16(&AOb[(size_t)(m0 + row_) * 256 + k0_ + ch_ * 8],           \
                    &Ad_[r0_ * 64]);                                           \
            GLOAD16(&Wob[(size_t)(n0 + row_) * 256 + k0_ + ch_ * 8],           \
                    &Bd_[r0_ * 64]);                                           \
        }                                                                      \
    }

    STAGE_OP(0, 0)
    __syncthreads();
    int cur = 0;
    for (int ki = 0; ki < 4; ++ki) {
        if (ki < 3) STAGE_OP(cur ^ 1, ki + 1)
        const ushort* A = lds + cur * 8192;
        const ushort* B = lds + 16384 + cur * 8192;
#pragma unroll
        for (int ks = 0; ks < 2; ++ks) {
            const int ko = ks * 32 + g * 8;
            short8 am[4], bn[4];
#pragma unroll
            for (int mi = 0; mi < 4; ++mi) {
                int row = wm * 64 + mi * 16 + c;
                am[mi] = *(const short8*)&A[row * 64 + (ko ^ ((row & 7) << 3))];
            }
#pragma unroll
            for (int ni = 0; ni < 4; ++ni) {
                int row = wn * 64 + ni * 16 + c;
                bn[ni] = *(const short8*)&B[row * 64 + (ko ^ ((row & 7) << 3))];
            }
#pragma unroll
            for (int mi = 0; mi < 4; ++mi)
#pragma unroll
                for (int ni = 0; ni < 4; ++ni)
                    acc[mi][ni] = __builtin_amdgcn_mfma_f32_16x16x32_bf16(
                        am[mi], bn[ni], acc[mi][ni], 0, 0, 0);
        }
        __syncthreads();
        cur ^= 1;
    }

    const int bidx = m0 >> 11;
#pragma unroll
    for (int ni = 0; ni < 4; ++ni) {
        int n = n0 + wn * 64 + ni * 16 + c;
        float mxv = -1e30f;
#pragma unroll
        for (int mi = 0; mi < 4; ++mi)
#pragma unroll
            for (int r = 0; r < 4; ++r) mxv = fmaxf(mxv, acc[mi][ni][r]);
        mxv += bias[n];
        mxv = fmaxf(mxv, __shfl_xor(mxv, 16));
        mxv = fmaxf(mxv, __shfl_xor(mxv, 32));
        if (lane < 16) {
            unsigned bits = __float_as_uint(mxv);
            unsigned en = (bits & 0x80000000u) ? ~bits : (bits | 0x80000000u);
            atomicMax(&CTX[bidx * 256 + n], en);
        }
    }
}

// ---------------------------------------------------------------------------
// K4a: fc1 + leaky_relu, PARALLEL: 64 blocks = (row, 8 chunks of 64 outputs).
// Each output: 4 lanes x 64-K slices, shfl reduce.
// ---------------------------------------------------------------------------
__global__ __launch_bounds__(256) void k_fc1(
    const unsigned* __restrict__ CTX, const float* __restrict__ w,
    const float* __restrict__ bias, float* __restrict__ H1)
{
    __shared__ float cs[256];
    const int tid = threadIdx.x;
    const int row = blockIdx.x >> 3, chunk = blockIdx.x & 7;
    unsigned u = CTX[row * 256 + tid];
    unsigned bits = (u & 0x80000000u) ? (u & 0x7fffffffu) : ~u;
    cs[tid] = __uint_as_float(bits);
    __syncthreads();
    const int o = chunk * 64 + (tid >> 2);      // output col
    const int k0 = (tid & 3) * 64;              // K-slice
    float a = 0.f;
#pragma unroll 16
    for (int i = 0; i < 16; ++i) {
        float4 w4 = *(const float4*)&w[o * 256 + k0 + i * 4];
        a = fmaf(w4.x, cs[k0 + i * 4 + 0], a);
        a = fmaf(w4.y, cs[k0 + i * 4 + 1], a);
        a = fmaf(w4.z, cs[k0 + i * 4 + 2], a);
        a = fmaf(w4.w, cs[k0 + i * 4 + 3], a);
    }
    a += __shfl_xor(a, 1);
    a += __shfl_xor(a, 2);
    if ((tid & 3) == 0) {
        a += bias[o];
        H1[row * 512 + o] = a > 0.f ? a : 0.01f * a;
    }
}

// ---------------------------------------------------------------------------
// K4b: fc2 + leaky_relu, PARALLEL: 64 blocks = (row, 8 chunks of 32 outputs).
// Each output: 8 lanes x 64-K slices, shfl reduce.
// ---------------------------------------------------------------------------
__global__ __launch_bounds__(256) void k_fc2(
    const float* __restrict__ H1, const float* __restrict__ w,
    const float* __restrict__ bias, float* __restrict__ H2)
{
    __shared__ float hs[512];
    const int tid = threadIdx.x;
    const int row = blockIdx.x >> 3, chunk = blockIdx.x & 7;
    hs[tid] = H1[row * 512 + tid];
    hs[tid + 256] = H1[row * 512 + tid + 256];
    __syncthreads();
    const int o = chunk * 32 + (tid >> 3);      // output col (0..255)
    const int k0 = (tid & 7) * 64;              // K-slice
    float a = 0.f;
#pragma unroll 16
    for (int i = 0; i < 16; ++i) {
        float4 w4 = *(const float4*)&w[o * 512 + k0 + i * 4];
        a = fmaf(w4.x, hs[k0 + i * 4 + 0], a);
        a = fmaf(w4.y, hs[k0 + i * 4 + 1], a);
        a = fmaf(w4.z, hs[k0 + i * 4 + 2], a);
        a = fmaf(w4.w, hs[k0 + i * 4 + 3], a);
    }
    a += __shfl_xor(a, 1);
    a += __shfl_xor(a, 2);
    a += __shfl_xor(a, 4);
    if ((tid & 7) == 0) {
        a += bias[o];
        H2[row * 256 + o] = a > 0.f ? a : 0.01f * a;
    }
}

// ---------------------------------------------------------------------------
// K4c: fc3, single small block (20 KB weights, K=256).
// ---------------------------------------------------------------------------
__global__ __launch_bounds__(256) void k_fc3(
    const float* __restrict__ H2, const float* __restrict__ w,
    const float* __restrict__ bias, float* __restrict__ out)
{
    __shared__ float hs[8][260];
    const int tid = threadIdx.x;
    for (int i = tid; i < 2048; i += 256) hs[i >> 8][i & 255] = H2[i];
    __syncthreads();
    if (tid < 160) {
        int r = tid / 20, o = tid % 20;
        float a = bias[o];
#pragma unroll 8
        for (int c4 = 0; c4 < 64; ++c4) {
            float4 w4 = *(const float4*)&w[o * 256 + c4 * 4];
            a = fmaf(w4.x, hs[r][c4 * 4 + 0], a);
            a = fmaf(w4.y, hs[r][c4 * 4 + 1], a);
            a = fmaf(w4.z, hs[r][c4 * 4 + 2], a);
            a = fmaf(w4.w, hs[r][c4 * 4 + 3], a);
        }
        out[tid] = a;
    }
}

// ---------------------------------------------------------------------------
extern "C" void kernel_launch(void* const* d_in, const int* in_sizes, int n_in,
                              void* d_out, int out_size, void* d_ws, size_t ws_size,
                              hipStream_t stream)
{
    (void)in_sizes; (void)n_in; (void)out_size; (void)ws_size;
    const int*   text = (const int*)d_in[0];
    const float* emb  = (const float*)d_in[1];
    const float* ipw  = (const float*)d_in[2];
    const float* ipb  = (const float*)d_in[3];
    const float* opw  = (const float*)d_in[4];
    const float* opb  = (const float*)d_in[5];
    const float* f1w  = (const float*)d_in[6];
    const float* f1b  = (const float*)d_in[7];
    const float* f2w  = (const float*)d_in[8];
    const float* f2b  = (const float*)d_in[9];
    const float* f3w  = (const float*)d_in[10];
    const float* f3b  = (const float*)d_in[11];
    float* out = (float*)d_out;

    // workspace ~42.6 MB (67 MB proven available)
    unsigned char* w8 = (unsigned char*)d_ws;
    ushort* Xb  = (ushort*)(w8);                    // 8 MiB [16384][256]
    ushort* Qb  = (ushort*)(w8 + 8388608);          // 8 MiB [B,H,S,64]
    ushort* Kb  = (ushort*)(w8 + 16777216);         // 8 MiB [B,H,S,64]
    ushort* VTb = (ushort*)(w8 + 25165824);         // 8 MiB [B,H,64,S]
    // 64 KiB gap: OOB window reads past VTb stay finite
    ushort* AOb = (ushort*)(w8 + 33619968);         // 8 MiB [B,S,256]
    ushort* Wqb = (ushort*)(w8 + 42008576);         // 384 KiB
    ushort* Wob = (ushort*)(w8 + 42401792);         // 128 KiB
    unsigned* CTX = (unsigned*)(w8 + 42532864);     // 8 KiB
    float* H1 = (float*)(w8 + 42541056);            // 16 KiB [8][512]
    float* H2 = (float*)(w8 + 42557440);            // 8 KiB  [8][256]

    hipFuncSetAttribute((const void*)k_qkv,
                        hipFuncAttributeMaxDynamicSharedMemorySize, 65536);
    hipFuncSetAttribute((const void*)k_oproj,
                        hipFuncAttributeMaxDynamicSharedMemorySize, 65536);

    hipMemsetAsync(CTX, 0, 8192, stream);
    k_prep<<<1088, 256, 0, stream>>>(text, emb, ipw, opw, Xb, Wqb, Wob);
    k_qkv<<<dim3(128, 6), 256, 65536, stream>>>(Xb, Wqb, ipb, Qb, Kb, VTb);
    k_attn<<<dim3(32, 4, 8), 256, 0, stream>>>(Qb, Kb, VTb, AOb);
    k_oproj<<<dim3(128, 2), 256, 65536, stream>>>(AOb, Wob, opb, CTX);
    k_fc1<<<64, 256, 0, stream>>>(CTX, f1w, f1b, H1);
    k_fc2<<<64, 256, 0, stream>>>(H1, f2w, f2b, H2);
    k_fc3<<<1, 256, 0, stream>>>(H2, f3w, f3b, out);
}